// Round 4
// baseline (806.852 us; speedup 1.0000x reference)
//
#include <hip/hip_runtime.h>
#include <hip/hip_bf16.h>

#define DEVI __device__ __forceinline__

using bf16x8 = __attribute__((ext_vector_type(8))) __bf16;
using f32x4  = __attribute__((ext_vector_type(4))) float;

DEVI unsigned short f2bf(float f) {
  unsigned int u = __float_as_uint(f);
  u = (u + 0x7FFFu + ((u >> 16) & 1u)) >> 16;
  return (unsigned short)u;
}
DEVI float bf2f(unsigned short s) { return __uint_as_float(((unsigned int)s) << 16); }

// ---------------- transpose + cast f32 -> bf16 : out[C][R] = in[R][C] ----------------
__global__ __launch_bounds__(256) void transpose_cast_kernel(const float* __restrict__ in,
                                                             unsigned short* __restrict__ out,
                                                             int R, int C) {
  __shared__ float tile[32][33];
  const int c0 = blockIdx.x * 32, r0 = blockIdx.y * 32;
  const int tx = threadIdx.x & 31, ty = threadIdx.x >> 5;  // 32 x 8
  for (int rr = ty; rr < 32; rr += 8)
    tile[rr][tx] = in[(size_t)(r0 + rr) * C + c0 + tx];
  __syncthreads();
  for (int cc = ty; cc < 32; cc += 8)
    out[(size_t)(c0 + cc) * R + r0 + tx] = f2bf(tile[tx][cc]);
}

// ---------------- RMSNorm: xn = x / max(||x||,eps) * sqrt(1024) * gamma, bf16 out ----
__global__ __launch_bounds__(256) void rmsnorm_kernel(const float* __restrict__ x,
                                                      const float* __restrict__ gamma,
                                                      unsigned short* __restrict__ xn) {
  __shared__ float wsum[4];
  const int row = blockIdx.x;
  const int t = threadIdx.x;
  const float4 v = *(const float4*)&x[(size_t)row * 1024 + t * 4];
  float s = v.x * v.x + v.y * v.y + v.z * v.z + v.w * v.w;
  for (int off = 32; off; off >>= 1) s += __shfl_down(s, off);
  if ((t & 63) == 0) wsum[t >> 6] = s;
  __syncthreads();
  const float tot = wsum[0] + wsum[1] + wsum[2] + wsum[3];
  const float scale = 32.0f / fmaxf(sqrtf(tot), 1e-12f);
  const float4 g = *(const float4*)&gamma[t * 4];
  ushort4 o;
  o.x = f2bf(v.x * scale * g.x);
  o.y = f2bf(v.y * scale * g.y);
  o.z = f2bf(v.z * scale * g.z);
  o.w = f2bf(v.w * scale * g.w);
  *(ushort4*)&xn[(size_t)row * 1024 + t * 4] = o;
}

// ---------------- bf16 MFMA GEMM: C[M,N] = A[M,K] @ Bt[N,K]^T, f32 out --------------
__global__ __launch_bounds__(256) void gemm_bt_f32out_kernel(const unsigned short* __restrict__ A,
                                                             const unsigned short* __restrict__ Bt,
                                                             float* __restrict__ C,
                                                             int M, int N, int K) {
  __shared__ __align__(16) unsigned short Al[128 * 32];
  __shared__ __align__(16) unsigned short Bl[128 * 32];
  const int tid = threadIdx.x;
  const int lane = tid & 63, wid = tid >> 6;
  const int wr = wid >> 1, wc = wid & 1;
  const int r = lane & 15, kg = lane >> 4;
  const size_t row0 = (size_t)blockIdx.y * 128, col0 = (size_t)blockIdx.x * 128;
  f32x4 acc[4][4] = {};
  for (int k0 = 0; k0 < K; k0 += 32) {
    __syncthreads();
    for (int c = tid; c < 512; c += 256) {
      const int rw = c >> 2, q = (c & 3) * 8;
      *(int4*)&Al[rw * 32 + q] = *(const int4*)&A[(row0 + rw) * K + k0 + q];
      *(int4*)&Bl[rw * 32 + q] = *(const int4*)&Bt[(col0 + rw) * K + k0 + q];
    }
    __syncthreads();
    bf16x8 af[4], bfr[4];
#pragma unroll
    for (int m = 0; m < 4; ++m) af[m] = *(const bf16x8*)&Al[(wr * 64 + m * 16 + r) * 32 + kg * 8];
#pragma unroll
    for (int n = 0; n < 4; ++n) bfr[n] = *(const bf16x8*)&Bl[(wc * 64 + n * 16 + r) * 32 + kg * 8];
#pragma unroll
    for (int m = 0; m < 4; ++m)
#pragma unroll
      for (int n = 0; n < 4; ++n)
        acc[m][n] = __builtin_amdgcn_mfma_f32_16x16x32_bf16(af[m], bfr[n], acc[m][n], 0, 0, 0);
  }
  const int rbase = wr * 64 + (lane >> 4) * 4;
  const int cbase = wc * 64 + (lane & 15);
#pragma unroll
  for (int m = 0; m < 4; ++m)
#pragma unroll
    for (int n = 0; n < 4; ++n)
#pragma unroll
      for (int j = 0; j < 4; ++j)
        C[(row0 + rbase + m * 16 + j) * N + col0 + cbase + n * 16] = acc[m][n][j];
}

// ---------------- qkv GEMM: A=xn[32768,1024], Bt=wqkvT[3072,1024] -------------------
// cols 0..2047 (q,k) -> qk[32768][2048] bf16; cols 2048..3071 (v) -> origv[b,h,d,n] f32
__global__ __launch_bounds__(256) void gemm_qkv_kernel(const unsigned short* __restrict__ A,
                                                       const unsigned short* __restrict__ Bt,
                                                       unsigned short* __restrict__ qk,
                                                       float* __restrict__ origv) {
  __shared__ __align__(16) unsigned short Al[128 * 32];
  __shared__ __align__(16) unsigned short Bl[128 * 32];
  const int tid = threadIdx.x;
  const int lane = tid & 63, wid = tid >> 6;
  const int wr = wid >> 1, wc = wid & 1;
  const int r = lane & 15, kg = lane >> 4;
  const size_t row0 = (size_t)blockIdx.y * 128, col0 = (size_t)blockIdx.x * 128;
  const int K = 1024;
  f32x4 acc[4][4] = {};
  for (int k0 = 0; k0 < K; k0 += 32) {
    __syncthreads();
    for (int c = tid; c < 512; c += 256) {
      const int rw = c >> 2, q = (c & 3) * 8;
      *(int4*)&Al[rw * 32 + q] = *(const int4*)&A[(row0 + rw) * K + k0 + q];
      *(int4*)&Bl[rw * 32 + q] = *(const int4*)&Bt[(col0 + rw) * K + k0 + q];
    }
    __syncthreads();
    bf16x8 af[4], bfr[4];
#pragma unroll
    for (int m = 0; m < 4; ++m) af[m] = *(const bf16x8*)&Al[(wr * 64 + m * 16 + r) * 32 + kg * 8];
#pragma unroll
    for (int n = 0; n < 4; ++n) bfr[n] = *(const bf16x8*)&Bl[(wc * 64 + n * 16 + r) * 32 + kg * 8];
#pragma unroll
    for (int m = 0; m < 4; ++m)
#pragma unroll
      for (int n = 0; n < 4; ++n)
        acc[m][n] = __builtin_amdgcn_mfma_f32_16x16x32_bf16(af[m], bfr[n], acc[m][n], 0, 0, 0);
  }
  const int rbase = wr * 64 + (lane >> 4) * 4;
  const int cbase = wc * 64 + (lane & 15);
  if (col0 < 2048) {
#pragma unroll
    for (int m = 0; m < 4; ++m)
#pragma unroll
      for (int n = 0; n < 4; ++n)
#pragma unroll
        for (int j = 0; j < 4; ++j)
          qk[(row0 + rbase + m * 16 + j) * 2048 + col0 + cbase + n * 16] = f2bf(acc[m][n][j]);
  } else {
    const int b = (int)(row0 >> 13);
    const int nn0 = (int)(row0 & 8191) + rbase;
#pragma unroll
    for (int m = 0; m < 4; ++m)
#pragma unroll
      for (int n = 0; n < 4; ++n) {
        const int hd = (int)(col0 - 2048) + cbase + n * 16;  // 0..1023 = h*64+d
        float4 o4;
        o4.x = acc[m][n][0];
        o4.y = acc[m][n][1];
        o4.z = acc[m][n][2];
        o4.w = acc[m][n][3];
        *(float4*)&origv[((size_t)b * 1024 + hd) * 8192 + nn0 + m * 16] = o4;
      }
  }
}

// ---------------- standalone norms: nrm[bh][oct][0/1][d] = partial sum of q^2 / k^2 --
__global__ __launch_bounds__(256) void attn_norms_kernel(const unsigned short* __restrict__ qkb,
                                                         float* __restrict__ nrm) {
  __shared__ float a[2][4][64];
  const int oct = blockIdx.x, bh = blockIdx.y;
  const int b = bh >> 4, h = bh & 15;
  const int t = threadIdx.x, d = t & 63, sub = t >> 6;
  const unsigned short* qb = qkb + (size_t)b * 8192 * 2048 + h * 64;
  const unsigned short* kb = qb + 1024;
  float sq = 0.f, sk = 0.f;
  const int nbeg = oct * 1024 + sub * 256;
  for (int n = nbeg; n < nbeg + 256; ++n) {
    const float qv = bf2f(qb[(size_t)n * 2048 + d]);
    const float kv = bf2f(kb[(size_t)n * 2048 + d]);
    sq += qv * qv;
    sk += kv * kv;
  }
  a[0][sub][d] = sq;
  a[1][sub][d] = sk;
  __syncthreads();
  if (t < 64)
    nrm[((size_t)(bh * 8 + oct) * 2 + 0) * 64 + t] = a[0][0][t] + a[0][1][t] + a[0][2][t] + a[0][3][t];
  else if (t < 128)
    nrm[((size_t)(bh * 8 + oct) * 2 + 1) * 64 + (t - 64)] =
        a[1][0][t - 64] + a[1][1][t - 64] + a[1][2][t - 64] + a[1][3][t - 64];
}

// ---------------- attention partial: S_raw[64x64] per (bh, chunk) --------------------
__global__ __launch_bounds__(256) void attn_partial_kernel(const unsigned short* __restrict__ qk,
                                                           float* __restrict__ part) {
  __shared__ float Qs[64][64];
  __shared__ float Ks[64][64];
  const int bh = blockIdx.y, chunk = blockIdx.x;
  const int b = bh >> 4, h = bh & 15;
  const int t = threadIdx.x;
  const int e = t & 63, g = t >> 6;
  const unsigned short* qbase = qk + (size_t)b * 8192 * 2048 + h * 64;
  const unsigned short* kbase = qbase + 1024;
  float s[16];
#pragma unroll
  for (int i = 0; i < 16; ++i) s[i] = 0.f;
  for (int it = 0; it < 16; ++it) {
    const int n0 = chunk * 1024 + it * 64;
    __syncthreads();
    for (int c = t; c < 1024; c += 256) {
      const int nn = c >> 4, q4 = (c & 15) * 4;
      const size_t go = (size_t)(n0 + nn) * 2048 + q4;
      const ushort4 uq = *(const ushort4*)&qbase[go];
      const ushort4 uk = *(const ushort4*)&kbase[go];
      Qs[nn][q4 + 0] = bf2f(uq.x); Qs[nn][q4 + 1] = bf2f(uq.y);
      Qs[nn][q4 + 2] = bf2f(uq.z); Qs[nn][q4 + 3] = bf2f(uq.w);
      Ks[nn][q4 + 0] = bf2f(uk.x); Ks[nn][q4 + 1] = bf2f(uk.y);
      Ks[nn][q4 + 2] = bf2f(uk.z); Ks[nn][q4 + 3] = bf2f(uk.w);
    }
    __syncthreads();
#pragma unroll 4
    for (int nn = 0; nn < 64; ++nn) {
      const float kv = Ks[nn][e];
      const float4 q0 = *(const float4*)&Qs[nn][g * 16 + 0];
      const float4 q1 = *(const float4*)&Qs[nn][g * 16 + 4];
      const float4 q2 = *(const float4*)&Qs[nn][g * 16 + 8];
      const float4 q3 = *(const float4*)&Qs[nn][g * 16 + 12];
      s[0] += q0.x * kv; s[1] += q0.y * kv; s[2] += q0.z * kv; s[3] += q0.w * kv;
      s[4] += q1.x * kv; s[5] += q1.y * kv; s[6] += q1.z * kv; s[7] += q1.w * kv;
      s[8] += q2.x * kv; s[9] += q2.y * kv; s[10] += q2.z * kv; s[11] += q2.w * kv;
      s[12] += q3.x * kv; s[13] += q3.y * kv; s[14] += q3.z * kv; s[15] += q3.w * kv;
    }
  }
  float* pb = part + (size_t)(bh * 8 + chunk) * 4096;
#pragma unroll
  for (int i = 0; i < 16; ++i) pb[(g * 16 + i) * 64 + e] = s[i];
}

// ---------------- reduce partials, normalize, softmax -> attn^T [e][d] ---------------
__global__ __launch_bounds__(256) void attn_reduce_kernel(const float* __restrict__ part,
                                                          const float* __restrict__ nrm,
                                                          const float* __restrict__ temperature,
                                                          float* __restrict__ attnt) {
  __shared__ float qn[64], kn[64];
  const int bh = blockIdx.x;
  const int h = bh & 15;
  const int t = threadIdx.x;
  const int e = t & 63, g = t >> 6;
  if (t < 64) {
    float s2 = 0.f;
    for (int c = 0; c < 8; ++c) s2 += nrm[((size_t)(bh * 8 + c) * 2 + 0) * 64 + t];
    qn[t] = fmaxf(sqrtf(s2), 1e-12f);
  } else if (t < 128) {
    float s2 = 0.f;
    for (int c = 0; c < 8; ++c) s2 += nrm[((size_t)(bh * 8 + c) * 2 + 1) * 64 + (t - 64)];
    kn[t - 64] = fmaxf(sqrtf(s2), 1e-12f);
  }
  __syncthreads();
  const float sc = 8.f * expf(temperature[h]);
  float sim[16];
#pragma unroll
  for (int i = 0; i < 16; ++i) {
    const int d = g * 16 + i;
    float s = 0.f;
    for (int c = 0; c < 8; ++c) s += part[(size_t)(bh * 8 + c) * 4096 + d * 64 + e];
    sim[i] = sc * s / (qn[d] * kn[e]);
  }
#pragma unroll
  for (int i = 0; i < 16; ++i) {
    float m = sim[i];
    for (int off = 32; off; off >>= 1) m = fmaxf(m, __shfl_xor(m, off));
    const float p = expf(sim[i] - m);
    float ssum = p;
    for (int off = 32; off; off >>= 1) ssum += __shfl_xor(ssum, off);
    attnt[(size_t)bh * 4096 + e * 64 + g * 16 + i] = p / ssum;
  }
}

// ---------------- PV pass: out[d][n] = sum_e attn[d][e] v[e][n], v from origv (f32) --
__global__ __launch_bounds__(256) void attn_pv_kernel(const float* __restrict__ origv,
                                                      const float* __restrict__ attnt,
                                                      unsigned short* __restrict__ ao) {
  __shared__ float At[64][64];   // [e][d]
  __shared__ float Vs[64][65];   // [e][n] (later reused as out[d][n])
  const int bh = blockIdx.y, chunk = blockIdx.x;
  const int b = bh >> 4, h = bh & 15;
  const int t = threadIdx.x;
  const int nl = t & 63, g = t >> 6;
  const float* vb = origv + (size_t)bh * 64 * 8192;
  for (int c = t; c < 1024; c += 256)
    *(float4*)&At[c >> 4][(c & 15) * 4] = *(const float4*)&attnt[(size_t)bh * 4096 + c * 4];
  for (int it = 0; it < 16; ++it) {
    const int n0 = chunk * 1024 + it * 64;
    __syncthreads();
    for (int c = t; c < 1024; c += 256) {
      const int ee = c >> 4, n4 = (c & 15) * 4;
      *(float4*)&Vs[ee][n4] = *(const float4*)&vb[(size_t)ee * 8192 + n0 + n4];
    }
    __syncthreads();
    float o[16];
#pragma unroll
    for (int i = 0; i < 16; ++i) o[i] = 0.f;
#pragma unroll 4
    for (int ee = 0; ee < 64; ++ee) {
      const float vv = Vs[ee][nl];
      const float4 a0 = *(const float4*)&At[ee][g * 16 + 0];
      const float4 a1 = *(const float4*)&At[ee][g * 16 + 4];
      const float4 a2 = *(const float4*)&At[ee][g * 16 + 8];
      const float4 a3 = *(const float4*)&At[ee][g * 16 + 12];
      o[0] += a0.x * vv; o[1] += a0.y * vv; o[2] += a0.z * vv; o[3] += a0.w * vv;
      o[4] += a1.x * vv; o[5] += a1.y * vv; o[6] += a1.z * vv; o[7] += a1.w * vv;
      o[8] += a2.x * vv; o[9] += a2.y * vv; o[10] += a2.z * vv; o[11] += a2.w * vv;
      o[12] += a3.x * vv; o[13] += a3.y * vv; o[14] += a3.z * vv; o[15] += a3.w * vv;
    }
    __syncthreads();
#pragma unroll
    for (int i = 0; i < 16; ++i) Vs[g * 16 + i][nl] = o[i];
    __syncthreads();
    {  // ao: [b, n, h*64+d] bf16 for the final GEMM
      const int n2 = t >> 2, c4 = t & 3;
      __attribute__((aligned(16))) unsigned short buf[16];
#pragma unroll
      for (int j = 0; j < 16; ++j) buf[j] = f2bf(Vs[c4 * 16 + j][n2]);
      ushort4* dst = (ushort4*)&ao[((size_t)b * 8192 + n0 + n2) * 1024 + h * 64 + c4 * 16];
      const ushort4* src = (const ushort4*)buf;
      dst[0] = src[0]; dst[1] = src[1]; dst[2] = src[2]; dst[3] = src[3];
    }
  }
}

extern "C" void kernel_launch(void* const* d_in, const int* in_sizes, int n_in,
                              void* d_out, int out_size, void* d_ws, size_t ws_size,
                              hipStream_t stream) {
  const float* x     = (const float*)d_in[0];
  const float* gamma = (const float*)d_in[1];
  const float* w_qkv = (const float*)d_in[2];
  const float* temp  = (const float*)d_in[3];
  const float* w_out = (const float*)d_in[4];
  char* ws = (char*)d_ws;
  unsigned short* wqkvT = (unsigned short*)(ws);                // [3072][1024] bf16, 6.3 MB
  unsigned short* woutT = (unsigned short*)(ws + 6291456);      // [1024][1024] bf16, 2.1 MB
  unsigned short* xn    = (unsigned short*)(ws + 8388608);      // [32768][1024] bf16, 67 MB
  unsigned short* qkb   = (unsigned short*)(ws + 75497472);     // [32768][2048] bf16, 134 MB
  float* part  = (float*)(ws + 209715200);                      // 64*8*4096 f32, 8.39 MB
  float* nrm   = (float*)(ws + 218103808);                      // 64*8*2*64 f32, 256 KB
  float* attnt = (float*)(ws + 218365952);                      // 64*4096 f32, 1 MB (end 219.4 MB)
  unsigned short* ao = qkb;                                     // reuse qkb (dead after norms/partial)
  float* outp  = (float*)d_out;                                 // out: [4,8192,1024] f32
  float* origv = outp + (size_t)33554432;                       // orig_v: [4,16,64,8192] f32

  transpose_cast_kernel<<<dim3(96, 32), 256, 0, stream>>>(w_qkv, wqkvT, 1024, 3072);
  transpose_cast_kernel<<<dim3(32, 32), 256, 0, stream>>>(w_out, woutT, 1024, 1024);
  rmsnorm_kernel<<<32768, 256, 0, stream>>>(x, gamma, xn);
  gemm_qkv_kernel<<<dim3(24, 256), 256, 0, stream>>>(xn, wqkvT, qkb, origv);
  attn_partial_kernel<<<dim3(8, 64), 256, 0, stream>>>(qkb, part);
  attn_norms_kernel<<<dim3(8, 64), 256, 0, stream>>>(qkb, nrm);
  attn_reduce_kernel<<<64, 256, 0, stream>>>(part, nrm, temp, attnt);
  attn_pv_kernel<<<dim3(8, 64), 256, 0, stream>>>(origv, attnt, ao);
  gemm_bt_f32out_kernel<<<dim3(8, 256), 256, 0, stream>>>(ao, woutT, outp, 32768, 1024, 1024);
}

// Round 5
// 708.409 us; speedup vs baseline: 1.1390x; 1.1390x over previous
//
#include <hip/hip_runtime.h>
#include <hip/hip_bf16.h>

#define DEVI __device__ __forceinline__

using bf16x8 = __attribute__((ext_vector_type(8))) __bf16;
using f32x4  = __attribute__((ext_vector_type(4))) float;

DEVI unsigned short f2bf(float f) {
  unsigned int u = __float_as_uint(f);
  u = (u + 0x7FFFu + ((u >> 16) & 1u)) >> 16;
  return (unsigned short)u;
}
DEVI float bf2f(unsigned short s) { return __uint_as_float(((unsigned int)s) << 16); }

// async global->LDS, 16B per lane; LDS dest must be wave-uniform-base + lane*16
DEVI void gld_lds16(const unsigned short* g, unsigned short* l) {
  __builtin_amdgcn_global_load_lds(
      (const __attribute__((address_space(1))) void*)g,
      (__attribute__((address_space(3))) void*)l, 16, 0, 0);
}

// ---------------- transpose + cast f32 -> bf16 : out[C][R] = in[R][C] ----------------
__global__ __launch_bounds__(256) void transpose_cast_kernel(const float* __restrict__ in,
                                                             unsigned short* __restrict__ out,
                                                             int R, int C) {
  __shared__ float tile[32][33];
  const int c0 = blockIdx.x * 32, r0 = blockIdx.y * 32;
  const int tx = threadIdx.x & 31, ty = threadIdx.x >> 5;  // 32 x 8
  for (int rr = ty; rr < 32; rr += 8)
    tile[rr][tx] = in[(size_t)(r0 + rr) * C + c0 + tx];
  __syncthreads();
  for (int cc = ty; cc < 32; cc += 8)
    out[(size_t)(c0 + cc) * R + r0 + tx] = f2bf(tile[tx][cc]);
}

// ---------------- RMSNorm: xn = x / max(||x||,eps) * sqrt(1024) * gamma, bf16 out ----
__global__ __launch_bounds__(256) void rmsnorm_kernel(const float* __restrict__ x,
                                                      const float* __restrict__ gamma,
                                                      unsigned short* __restrict__ xn) {
  __shared__ float wsum[4];
  const int row = blockIdx.x;
  const int t = threadIdx.x;
  const float4 v = *(const float4*)&x[(size_t)row * 1024 + t * 4];
  float s = v.x * v.x + v.y * v.y + v.z * v.z + v.w * v.w;
  for (int off = 32; off; off >>= 1) s += __shfl_down(s, off);
  if ((t & 63) == 0) wsum[t >> 6] = s;
  __syncthreads();
  const float tot = wsum[0] + wsum[1] + wsum[2] + wsum[3];
  const float scale = 32.0f / fmaxf(sqrtf(tot), 1e-12f);
  const float4 g = *(const float4*)&gamma[t * 4];
  ushort4 o;
  o.x = f2bf(v.x * scale * g.x);
  o.y = f2bf(v.y * scale * g.y);
  o.z = f2bf(v.z * scale * g.z);
  o.w = f2bf(v.w * scale * g.w);
  *(ushort4*)&xn[(size_t)row * 1024 + t * 4] = o;
}

// ---------------- bf16 MFMA GEMM: C[M,N] = A[M,K] @ Bt[N,K]^T, f32 out --------------
// 128x128 tile, BK=32, global_load_lds(16B) staging. LDS layout is lane-linear.
__global__ __launch_bounds__(256) void gemm_bt_f32out_kernel(const unsigned short* __restrict__ A,
                                                             const unsigned short* __restrict__ Bt,
                                                             float* __restrict__ C,
                                                             int M, int N, int K) {
  __shared__ __align__(16) unsigned short Al[128 * 32];
  __shared__ __align__(16) unsigned short Bl[128 * 32];
  const int tid = threadIdx.x;
  const int lane = tid & 63, wid = tid >> 6;
  const int wr = wid >> 1, wc = wid & 1;
  const int r = lane & 15, kg = lane >> 4;
  const int rw0 = tid >> 2, q0 = (tid & 3) * 8;
  const size_t row0 = (size_t)blockIdx.y * 128, col0 = (size_t)blockIdx.x * 128;
  f32x4 acc[4][4] = {};
  for (int k0 = 0; k0 < K; k0 += 32) {
    __syncthreads();
    gld_lds16(&A[(row0 + rw0) * K + k0 + q0], &Al[tid * 8]);
    gld_lds16(&A[(row0 + rw0 + 64) * K + k0 + q0], &Al[2048 + tid * 8]);
    gld_lds16(&Bt[(col0 + rw0) * K + k0 + q0], &Bl[tid * 8]);
    gld_lds16(&Bt[(col0 + rw0 + 64) * K + k0 + q0], &Bl[2048 + tid * 8]);
    __syncthreads();
    bf16x8 af[4], bfr[4];
#pragma unroll
    for (int m = 0; m < 4; ++m) af[m] = *(const bf16x8*)&Al[(wr * 64 + m * 16 + r) * 32 + kg * 8];
#pragma unroll
    for (int n = 0; n < 4; ++n) bfr[n] = *(const bf16x8*)&Bl[(wc * 64 + n * 16 + r) * 32 + kg * 8];
#pragma unroll
    for (int m = 0; m < 4; ++m)
#pragma unroll
      for (int n = 0; n < 4; ++n)
        acc[m][n] = __builtin_amdgcn_mfma_f32_16x16x32_bf16(af[m], bfr[n], acc[m][n], 0, 0, 0);
  }
  const int rbase = wr * 64 + (lane >> 4) * 4;
  const int cbase = wc * 64 + (lane & 15);
#pragma unroll
  for (int m = 0; m < 4; ++m)
#pragma unroll
    for (int n = 0; n < 4; ++n)
#pragma unroll
      for (int j = 0; j < 4; ++j)
        C[(row0 + rbase + m * 16 + j) * N + col0 + cbase + n * 16] = acc[m][n][j];
}

// ---------------- qkv GEMM: A=xn[32768,1024], Bt=wqkvT[3072,1024] -------------------
// cols 0..2047 (q,k) -> qk[32768][2048] bf16; cols 2048..3071 (v) -> origv[b,h,d,n] f32
__global__ __launch_bounds__(256) void gemm_qkv_kernel(const unsigned short* __restrict__ A,
                                                       const unsigned short* __restrict__ Bt,
                                                       unsigned short* __restrict__ qk,
                                                       float* __restrict__ origv) {
  __shared__ __align__(16) unsigned short Al[128 * 32];
  __shared__ __align__(16) unsigned short Bl[128 * 32];
  const int tid = threadIdx.x;
  const int lane = tid & 63, wid = tid >> 6;
  const int wr = wid >> 1, wc = wid & 1;
  const int r = lane & 15, kg = lane >> 4;
  const int rw0 = tid >> 2, q0 = (tid & 3) * 8;
  const size_t row0 = (size_t)blockIdx.y * 128, col0 = (size_t)blockIdx.x * 128;
  const int K = 1024;
  f32x4 acc[4][4] = {};
  for (int k0 = 0; k0 < K; k0 += 32) {
    __syncthreads();
    gld_lds16(&A[(row0 + rw0) * K + k0 + q0], &Al[tid * 8]);
    gld_lds16(&A[(row0 + rw0 + 64) * K + k0 + q0], &Al[2048 + tid * 8]);
    gld_lds16(&Bt[(col0 + rw0) * K + k0 + q0], &Bl[tid * 8]);
    gld_lds16(&Bt[(col0 + rw0 + 64) * K + k0 + q0], &Bl[2048 + tid * 8]);
    __syncthreads();
    bf16x8 af[4], bfr[4];
#pragma unroll
    for (int m = 0; m < 4; ++m) af[m] = *(const bf16x8*)&Al[(wr * 64 + m * 16 + r) * 32 + kg * 8];
#pragma unroll
    for (int n = 0; n < 4; ++n) bfr[n] = *(const bf16x8*)&Bl[(wc * 64 + n * 16 + r) * 32 + kg * 8];
#pragma unroll
    for (int m = 0; m < 4; ++m)
#pragma unroll
      for (int n = 0; n < 4; ++n)
        acc[m][n] = __builtin_amdgcn_mfma_f32_16x16x32_bf16(af[m], bfr[n], acc[m][n], 0, 0, 0);
  }
  const int rbase = wr * 64 + (lane >> 4) * 4;
  const int cbase = wc * 64 + (lane & 15);
  if (col0 < 2048) {
#pragma unroll
    for (int m = 0; m < 4; ++m)
#pragma unroll
      for (int n = 0; n < 4; ++n)
#pragma unroll
        for (int j = 0; j < 4; ++j)
          qk[(row0 + rbase + m * 16 + j) * 2048 + col0 + cbase + n * 16] = f2bf(acc[m][n][j]);
  } else {
    const int b = (int)(row0 >> 13);
    const int nn0 = (int)(row0 & 8191) + rbase;
#pragma unroll
    for (int m = 0; m < 4; ++m)
#pragma unroll
      for (int n = 0; n < 4; ++n) {
        const int hd = (int)(col0 - 2048) + cbase + n * 16;  // 0..1023 = h*64+d
        float4 o4;
        o4.x = acc[m][n][0];
        o4.y = acc[m][n][1];
        o4.z = acc[m][n][2];
        o4.w = acc[m][n][3];
        *(float4*)&origv[((size_t)b * 1024 + hd) * 8192 + nn0 + m * 16] = o4;
      }
  }
}

// ---------------- attention partial: S_raw[64x64] + fused q/k sumsq per (bh, chunk) --
__global__ __launch_bounds__(256) void attn_partial_kernel(const unsigned short* __restrict__ qk,
                                                           float* __restrict__ part,
                                                           float* __restrict__ nrm) {
  __shared__ float Qs[64][64];
  __shared__ float Ks[64][64];
  __shared__ float red[2][4][64];
  const int bh = blockIdx.y, chunk = blockIdx.x;
  const int b = bh >> 4, h = bh & 15;
  const int t = threadIdx.x;
  const int e = t & 63, g = t >> 6;
  const unsigned short* qbase = qk + (size_t)b * 8192 * 2048 + h * 64;
  const unsigned short* kbase = qbase + 1024;
  float s[16];
#pragma unroll
  for (int i = 0; i < 16; ++i) s[i] = 0.f;
  float sq = 0.f, sk = 0.f;
  for (int it = 0; it < 16; ++it) {
    const int n0 = chunk * 1024 + it * 64;
    __syncthreads();
    for (int c = t; c < 1024; c += 256) {
      const int nn = c >> 4, q4 = (c & 15) * 4;
      const size_t go = (size_t)(n0 + nn) * 2048 + q4;
      const ushort4 uq = *(const ushort4*)&qbase[go];
      const ushort4 uk = *(const ushort4*)&kbase[go];
      Qs[nn][q4 + 0] = bf2f(uq.x); Qs[nn][q4 + 1] = bf2f(uq.y);
      Qs[nn][q4 + 2] = bf2f(uq.z); Qs[nn][q4 + 3] = bf2f(uq.w);
      Ks[nn][q4 + 0] = bf2f(uk.x); Ks[nn][q4 + 1] = bf2f(uk.y);
      Ks[nn][q4 + 2] = bf2f(uk.z); Ks[nn][q4 + 3] = bf2f(uk.w);
    }
    __syncthreads();
#pragma unroll 4
    for (int nn = 0; nn < 64; ++nn) {
      const float kv = Ks[nn][e];
      const float4 q0 = *(const float4*)&Qs[nn][g * 16 + 0];
      const float4 q1 = *(const float4*)&Qs[nn][g * 16 + 4];
      const float4 q2 = *(const float4*)&Qs[nn][g * 16 + 8];
      const float4 q3 = *(const float4*)&Qs[nn][g * 16 + 12];
      s[0] += q0.x * kv; s[1] += q0.y * kv; s[2] += q0.z * kv; s[3] += q0.w * kv;
      s[4] += q1.x * kv; s[5] += q1.y * kv; s[6] += q1.z * kv; s[7] += q1.w * kv;
      s[8] += q2.x * kv; s[9] += q2.y * kv; s[10] += q2.z * kv; s[11] += q2.w * kv;
      s[12] += q3.x * kv; s[13] += q3.y * kv; s[14] += q3.z * kv; s[15] += q3.w * kv;
    }
    // fused norms: thread (g,e) accumulates sumsq of column e over rows g*16..g*16+15
#pragma unroll
    for (int j = 0; j < 16; ++j) {
      const int nn = g * 16 + j;
      const float qv = Qs[nn][e];
      const float kv = Ks[nn][e];
      sq += qv * qv;
      sk += kv * kv;
    }
  }
  float* pb = part + (size_t)(bh * 8 + chunk) * 4096;
#pragma unroll
  for (int i = 0; i < 16; ++i) pb[(g * 16 + i) * 64 + e] = s[i];
  red[0][g][e] = sq;
  red[1][g][e] = sk;
  __syncthreads();
  if (t < 64)
    nrm[((size_t)(bh * 8 + chunk) * 2 + 0) * 64 + t] = red[0][0][t] + red[0][1][t] + red[0][2][t] + red[0][3][t];
  else if (t < 128)
    nrm[((size_t)(bh * 8 + chunk) * 2 + 1) * 64 + (t - 64)] =
        red[1][0][t - 64] + red[1][1][t - 64] + red[1][2][t - 64] + red[1][3][t - 64];
}

// ---------------- reduce partials, normalize, softmax -> attn^T [e][d] ---------------
__global__ __launch_bounds__(256) void attn_reduce_kernel(const float* __restrict__ part,
                                                          const float* __restrict__ nrm,
                                                          const float* __restrict__ temperature,
                                                          float* __restrict__ attnt) {
  __shared__ float qn[64], kn[64];
  const int bh = blockIdx.x;
  const int h = bh & 15;
  const int t = threadIdx.x;
  const int e = t & 63, g = t >> 6;
  if (t < 64) {
    float s2 = 0.f;
    for (int c = 0; c < 8; ++c) s2 += nrm[((size_t)(bh * 8 + c) * 2 + 0) * 64 + t];
    qn[t] = fmaxf(sqrtf(s2), 1e-12f);
  } else if (t < 128) {
    float s2 = 0.f;
    for (int c = 0; c < 8; ++c) s2 += nrm[((size_t)(bh * 8 + c) * 2 + 1) * 64 + (t - 64)];
    kn[t - 64] = fmaxf(sqrtf(s2), 1e-12f);
  }
  __syncthreads();
  const float sc = 8.f * expf(temperature[h]);
  float sim[16];
#pragma unroll
  for (int i = 0; i < 16; ++i) {
    const int d = g * 16 + i;
    float s = 0.f;
    for (int c = 0; c < 8; ++c) s += part[(size_t)(bh * 8 + c) * 4096 + d * 64 + e];
    sim[i] = sc * s / (qn[d] * kn[e]);
  }
#pragma unroll
  for (int i = 0; i < 16; ++i) {
    float m = sim[i];
    for (int off = 32; off; off >>= 1) m = fmaxf(m, __shfl_xor(m, off));
    const float p = expf(sim[i] - m);
    float ssum = p;
    for (int off = 32; off; off >>= 1) ssum += __shfl_xor(ssum, off);
    attnt[(size_t)bh * 4096 + e * 64 + g * 16 + i] = p / ssum;
  }
}

// ---------------- PV pass: out[d][n] = sum_e attn[d][e] v[e][n], v from origv (f32) --
__global__ __launch_bounds__(256) void attn_pv_kernel(const float* __restrict__ origv,
                                                      const float* __restrict__ attnt,
                                                      unsigned short* __restrict__ ao) {
  __shared__ float At[64][64];   // [e][d]
  __shared__ float Vs[64][65];   // [e][n] (later reused as out[d][n])
  const int bh = blockIdx.y, chunk = blockIdx.x;
  const int b = bh >> 4, h = bh & 15;
  const int t = threadIdx.x;
  const int nl = t & 63, g = t >> 6;
  const float* vb = origv + (size_t)bh * 64 * 8192;
  for (int c = t; c < 1024; c += 256)
    *(float4*)&At[c >> 4][(c & 15) * 4] = *(const float4*)&attnt[(size_t)bh * 4096 + c * 4];
  for (int it = 0; it < 16; ++it) {
    const int n0 = chunk * 1024 + it * 64;
    __syncthreads();
    for (int c = t; c < 1024; c += 256) {
      const int ee = c >> 4, n4 = (c & 15) * 4;
      *(float4*)&Vs[ee][n4] = *(const float4*)&vb[(size_t)ee * 8192 + n0 + n4];
    }
    __syncthreads();
    float o[16];
#pragma unroll
    for (int i = 0; i < 16; ++i) o[i] = 0.f;
#pragma unroll 4
    for (int ee = 0; ee < 64; ++ee) {
      const float vv = Vs[ee][nl];
      const float4 a0 = *(const float4*)&At[ee][g * 16 + 0];
      const float4 a1 = *(const float4*)&At[ee][g * 16 + 4];
      const float4 a2 = *(const float4*)&At[ee][g * 16 + 8];
      const float4 a3 = *(const float4*)&At[ee][g * 16 + 12];
      o[0] += a0.x * vv; o[1] += a0.y * vv; o[2] += a0.z * vv; o[3] += a0.w * vv;
      o[4] += a1.x * vv; o[5] += a1.y * vv; o[6] += a1.z * vv; o[7] += a1.w * vv;
      o[8] += a2.x * vv; o[9] += a2.y * vv; o[10] += a2.z * vv; o[11] += a2.w * vv;
      o[12] += a3.x * vv; o[13] += a3.y * vv; o[14] += a3.z * vv; o[15] += a3.w * vv;
    }
    __syncthreads();
#pragma unroll
    for (int i = 0; i < 16; ++i) Vs[g * 16 + i][nl] = o[i];
    __syncthreads();
    {  // ao: [b, n, h*64+d] bf16 for the final GEMM
      const int n2 = t >> 2, c4 = t & 3;
      __attribute__((aligned(16))) unsigned short buf[16];
#pragma unroll
      for (int j = 0; j < 16; ++j) buf[j] = f2bf(Vs[c4 * 16 + j][n2]);
      ushort4* dst = (ushort4*)&ao[((size_t)b * 8192 + n0 + n2) * 1024 + h * 64 + c4 * 16];
      const ushort4* src = (const ushort4*)buf;
      dst[0] = src[0]; dst[1] = src[1]; dst[2] = src[2]; dst[3] = src[3];
    }
  }
}

extern "C" void kernel_launch(void* const* d_in, const int* in_sizes, int n_in,
                              void* d_out, int out_size, void* d_ws, size_t ws_size,
                              hipStream_t stream) {
  const float* x     = (const float*)d_in[0];
  const float* gamma = (const float*)d_in[1];
  const float* w_qkv = (const float*)d_in[2];
  const float* temp  = (const float*)d_in[3];
  const float* w_out = (const float*)d_in[4];
  char* ws = (char*)d_ws;
  unsigned short* wqkvT = (unsigned short*)(ws);                // [3072][1024] bf16, 6.3 MB
  unsigned short* woutT = (unsigned short*)(ws + 6291456);      // [1024][1024] bf16, 2.1 MB
  unsigned short* xn    = (unsigned short*)(ws + 8388608);      // [32768][1024] bf16, 67 MB
  unsigned short* qkb   = (unsigned short*)(ws + 75497472);     // [32768][2048] bf16, 134 MB
  float* part  = (float*)(ws + 209715200);                      // 64*8*4096 f32, 8.39 MB
  float* nrm   = (float*)(ws + 218103808);                      // 64*8*2*64 f32, 256 KB
  float* attnt = (float*)(ws + 218365952);                      // 64*4096 f32, 1 MB (end 219.4 MB)
  unsigned short* ao = qkb;                                     // reuse qkb (dead after partial)
  float* outp  = (float*)d_out;                                 // out: [4,8192,1024] f32
  float* origv = outp + (size_t)33554432;                       // orig_v: [4,16,64,8192] f32

  transpose_cast_kernel<<<dim3(96, 32), 256, 0, stream>>>(w_qkv, wqkvT, 1024, 3072);
  transpose_cast_kernel<<<dim3(32, 32), 256, 0, stream>>>(w_out, woutT, 1024, 1024);
  rmsnorm_kernel<<<32768, 256, 0, stream>>>(x, gamma, xn);
  gemm_qkv_kernel<<<dim3(24, 256), 256, 0, stream>>>(xn, wqkvT, qkb, origv);
  attn_partial_kernel<<<dim3(8, 64), 256, 0, stream>>>(qkb, part, nrm);
  attn_reduce_kernel<<<64, 256, 0, stream>>>(part, nrm, temp, attnt);
  attn_pv_kernel<<<dim3(8, 64), 256, 0, stream>>>(origv, attnt, ao);
  gemm_bt_f32out_kernel<<<dim3(8, 256), 256, 0, stream>>>(ao, woutT, outp, 32768, 1024, 1024);
}

// Round 6
// 567.887 us; speedup vs baseline: 1.4208x; 1.2474x over previous
//
#include <hip/hip_runtime.h>
#include <hip/hip_bf16.h>

#define DEVI __device__ __forceinline__

using bf16x8 = __attribute__((ext_vector_type(8))) __bf16;
using f32x4  = __attribute__((ext_vector_type(4))) float;
using u16x8  = __attribute__((ext_vector_type(8))) unsigned short;

DEVI unsigned short f2bf(float f) {
  unsigned int u = __float_as_uint(f);
  u = (u + 0x7FFFu + ((u >> 16) & 1u)) >> 16;
  return (unsigned short)u;
}
DEVI float bf2f(unsigned short s) { return __uint_as_float(((unsigned int)s) << 16); }

// async global->LDS, 16B per lane; LDS dest must be wave-uniform-base + lane*16
DEVI void gld_lds16(const unsigned short* g, unsigned short* l) {
  __builtin_amdgcn_global_load_lds(
      (const __attribute__((address_space(1))) void*)g,
      (__attribute__((address_space(3))) void*)l, 16, 0, 0);
}

// ---------------- transpose + cast f32 -> bf16 : out[C][R] = in[R][C] ----------------
__global__ __launch_bounds__(256) void transpose_cast_kernel(const float* __restrict__ in,
                                                             unsigned short* __restrict__ out,
                                                             int R, int C) {
  __shared__ float tile[32][33];
  const int c0 = blockIdx.x * 32, r0 = blockIdx.y * 32;
  const int tx = threadIdx.x & 31, ty = threadIdx.x >> 5;
  for (int rr = ty; rr < 32; rr += 8)
    tile[rr][tx] = in[(size_t)(r0 + rr) * C + c0 + tx];
  __syncthreads();
  for (int cc = ty; cc < 32; cc += 8)
    out[(size_t)(c0 + cc) * R + r0 + tx] = f2bf(tile[tx][cc]);
}

// ---------------- transpose bf16 -> bf16 : out[C][R] = in[R][C] ----------------------
__global__ __launch_bounds__(256) void transpose_bf16_kernel(const unsigned short* __restrict__ in,
                                                             unsigned short* __restrict__ out,
                                                             int R, int C) {
  __shared__ unsigned short tile[32][33];
  const int c0 = blockIdx.x * 32, r0 = blockIdx.y * 32;
  const int tx = threadIdx.x & 31, ty = threadIdx.x >> 5;
  for (int rr = ty; rr < 32; rr += 8)
    tile[rr][tx] = in[(size_t)(r0 + rr) * C + c0 + tx];
  __syncthreads();
  for (int cc = ty; cc < 32; cc += 8)
    out[(size_t)(c0 + cc) * R + r0 + tx] = tile[tx][cc];
}

// ---------------- RMSNorm: xn = x / max(||x||,eps) * sqrt(1024) * gamma, bf16 out ----
__global__ __launch_bounds__(256) void rmsnorm_kernel(const float* __restrict__ x,
                                                      const float* __restrict__ gamma,
                                                      unsigned short* __restrict__ xn) {
  __shared__ float wsum[4];
  const int row = blockIdx.x;
  const int t = threadIdx.x;
  const float4 v = *(const float4*)&x[(size_t)row * 1024 + t * 4];
  float s = v.x * v.x + v.y * v.y + v.z * v.z + v.w * v.w;
  for (int off = 32; off; off >>= 1) s += __shfl_down(s, off);
  if ((t & 63) == 0) wsum[t >> 6] = s;
  __syncthreads();
  const float tot = wsum[0] + wsum[1] + wsum[2] + wsum[3];
  const float scale = 32.0f / fmaxf(sqrtf(tot), 1e-12f);
  const float4 g = *(const float4*)&gamma[t * 4];
  ushort4 o;
  o.x = f2bf(v.x * scale * g.x);
  o.y = f2bf(v.y * scale * g.y);
  o.z = f2bf(v.z * scale * g.z);
  o.w = f2bf(v.w * scale * g.w);
  *(ushort4*)&xn[(size_t)row * 1024 + t * 4] = o;
}

// ---------------- Gram: Gp[z] = xnT_b[:, ksplit] @ xnT_b[:, ksplit]^T (lower tiles) --
__global__ __launch_bounds__(256) void gemm_gram_kernel(const unsigned short* __restrict__ xnT,
                                                        unsigned short* __restrict__ Gp) {
  if (blockIdx.x > blockIdx.y) return;  // lower-triangle 128-tiles only
  __shared__ __align__(16) unsigned short Al[4096];
  __shared__ __align__(16) unsigned short Bl[4096];
  const int tid = threadIdx.x;
  const int lane = tid & 63, wid = tid >> 6;
  const int wr = wid >> 1, wc = wid & 1;
  const int r = lane & 15, kg = lane >> 4;
  const int rw0 = tid >> 2, q0 = (tid & 3) * 8;
  const size_t row0 = (size_t)blockIdx.y * 128, col0 = (size_t)blockIdx.x * 128;
  const int z = blockIdx.z;
  const size_t koff = (size_t)(z >> 2) * 8192 + (size_t)(z & 3) * 2048;
  f32x4 acc[4][4] = {};
  for (int k0 = 0; k0 < 2048; k0 += 32) {
    __syncthreads();
    gld_lds16(&xnT[(row0 + rw0) * 32768 + koff + k0 + q0], &Al[tid * 8]);
    gld_lds16(&xnT[(row0 + rw0 + 64) * 32768 + koff + k0 + q0], &Al[2048 + tid * 8]);
    gld_lds16(&xnT[(col0 + rw0) * 32768 + koff + k0 + q0], &Bl[tid * 8]);
    gld_lds16(&xnT[(col0 + rw0 + 64) * 32768 + koff + k0 + q0], &Bl[2048 + tid * 8]);
    __syncthreads();
    bf16x8 af[4], bfr[4];
#pragma unroll
    for (int m = 0; m < 4; ++m) af[m] = *(const bf16x8*)&Al[(wr * 64 + m * 16 + r) * 32 + kg * 8];
#pragma unroll
    for (int n = 0; n < 4; ++n) bfr[n] = *(const bf16x8*)&Bl[(wc * 64 + n * 16 + r) * 32 + kg * 8];
#pragma unroll
    for (int m = 0; m < 4; ++m)
#pragma unroll
      for (int n = 0; n < 4; ++n)
        acc[m][n] = __builtin_amdgcn_mfma_f32_16x16x32_bf16(af[m], bfr[n], acc[m][n], 0, 0, 0);
  }
  unsigned short* C = Gp + ((size_t)z << 20);
  const int rbase = wr * 64 + (lane >> 4) * 4;
  const int cbase = wc * 64 + (lane & 15);
#pragma unroll
  for (int m = 0; m < 4; ++m)
#pragma unroll
    for (int n = 0; n < 4; ++n)
#pragma unroll
      for (int j = 0; j < 4; ++j)
        C[(row0 + rbase + m * 16 + j) * 1024 + col0 + cbase + n * 16] = f2bf(acc[m][n][j]);
}

// ---------------- reduce split-K partials + mirror to full symmetric G (bf16) --------
__global__ __launch_bounds__(256) void greduce_kernel(const unsigned short* __restrict__ Gp,
                                                      unsigned short* __restrict__ G) {
  const int tj = blockIdx.x, ti = blockIdx.y, b = blockIdx.z;
  if ((tj >> 1) > (ti >> 1)) return;  // source 128-tile not computed
  __shared__ float lds[64][65];
  const int t = threadIdx.x;
  const int r = t >> 2, c0 = (t & 3) * 16;
  const size_t idx = (size_t)(ti * 64 + r) * 1024 + tj * 64 + c0;
  float v[16];
#pragma unroll
  for (int j = 0; j < 16; ++j) v[j] = 0.f;
  for (int s = 0; s < 4; ++s) {
    const unsigned short* p = Gp + ((size_t)(b * 4 + s) << 20) + idx;
#pragma unroll
    for (int j = 0; j < 16; ++j) v[j] += bf2f(p[j]);
  }
  unsigned short* Gb = G + ((size_t)b << 20);
  __attribute__((aligned(16))) unsigned short buf[16];
#pragma unroll
  for (int j = 0; j < 16; ++j) buf[j] = f2bf(v[j]);
  { int4* dst = (int4*)&Gb[idx]; const int4* src = (const int4*)buf; dst[0] = src[0]; dst[1] = src[1]; }
  if ((ti >> 1) != (tj >> 1)) {  // mirror to upper region (block-uniform branch)
#pragma unroll
    for (int j = 0; j < 16; ++j) lds[r][c0 + j] = v[j];
    __syncthreads();
    const int x = t >> 2, y0 = (t & 3) * 16;
#pragma unroll
    for (int j = 0; j < 16; ++j) buf[j] = f2bf(lds[y0 + j][x]);
    int4* dst = (int4*)&Gb[(size_t)(tj * 64 + x) * 1024 + ti * 64 + y0];
    const int4* src = (const int4*)buf;
    dst[0] = src[0]; dst[1] = src[1];
  }
}

// ---------------- batched bf16 GEMM: C[M,N] = A @ Bt^T, bf16 out ---------------------
__global__ __launch_bounds__(256) void gemm_bt_batch_bf16(const unsigned short* __restrict__ A,
                                                          const unsigned short* __restrict__ Bt,
                                                          unsigned short* __restrict__ C,
                                                          int N, int K,
                                                          long long aStr, long long bStr, long long cStr) {
  __shared__ __align__(16) unsigned short Al[4096];
  __shared__ __align__(16) unsigned short Bl[4096];
  A += (size_t)blockIdx.z * aStr; Bt += (size_t)blockIdx.z * bStr; C += (size_t)blockIdx.z * cStr;
  const int tid = threadIdx.x;
  const int lane = tid & 63, wid = tid >> 6;
  const int wr = wid >> 1, wc = wid & 1;
  const int r = lane & 15, kg = lane >> 4;
  const int rw0 = tid >> 2, q0 = (tid & 3) * 8;
  const size_t row0 = (size_t)blockIdx.y * 128, col0 = (size_t)blockIdx.x * 128;
  f32x4 acc[4][4] = {};
  for (int k0 = 0; k0 < K; k0 += 32) {
    __syncthreads();
    gld_lds16(&A[(row0 + rw0) * K + k0 + q0], &Al[tid * 8]);
    gld_lds16(&A[(row0 + rw0 + 64) * K + k0 + q0], &Al[2048 + tid * 8]);
    gld_lds16(&Bt[(col0 + rw0) * K + k0 + q0], &Bl[tid * 8]);
    gld_lds16(&Bt[(col0 + rw0 + 64) * K + k0 + q0], &Bl[2048 + tid * 8]);
    __syncthreads();
    bf16x8 af[4], bfr[4];
#pragma unroll
    for (int m = 0; m < 4; ++m) af[m] = *(const bf16x8*)&Al[(wr * 64 + m * 16 + r) * 32 + kg * 8];
#pragma unroll
    for (int n = 0; n < 4; ++n) bfr[n] = *(const bf16x8*)&Bl[(wc * 64 + n * 16 + r) * 32 + kg * 8];
#pragma unroll
    for (int m = 0; m < 4; ++m)
#pragma unroll
      for (int n = 0; n < 4; ++n)
        acc[m][n] = __builtin_amdgcn_mfma_f32_16x16x32_bf16(af[m], bfr[n], acc[m][n], 0, 0, 0);
  }
  const int rbase = wr * 64 + (lane >> 4) * 4;
  const int cbase = wc * 64 + (lane & 15);
#pragma unroll
  for (int m = 0; m < 4; ++m)
#pragma unroll
    for (int n = 0; n < 4; ++n)
#pragma unroll
      for (int j = 0; j < 4; ++j)
        C[(row0 + rbase + m * 16 + j) * N + col0 + cbase + n * 16] = f2bf(acc[m][n][j]);
}

// ---------------- batched bf16 GEMM: C[M,N] = A @ Bt^T, f32 out ----------------------
__global__ __launch_bounds__(256) void gemm_bt_batch_f32(const unsigned short* __restrict__ A,
                                                         const unsigned short* __restrict__ Bt,
                                                         float* __restrict__ C,
                                                         int N, int K,
                                                         long long aStr, long long bStr, long long cStr) {
  __shared__ __align__(16) unsigned short Al[4096];
  __shared__ __align__(16) unsigned short Bl[4096];
  A += (size_t)blockIdx.z * aStr; Bt += (size_t)blockIdx.z * bStr; C += (size_t)blockIdx.z * cStr;
  const int tid = threadIdx.x;
  const int lane = tid & 63, wid = tid >> 6;
  const int wr = wid >> 1, wc = wid & 1;
  const int r = lane & 15, kg = lane >> 4;
  const int rw0 = tid >> 2, q0 = (tid & 3) * 8;
  const size_t row0 = (size_t)blockIdx.y * 128, col0 = (size_t)blockIdx.x * 128;
  f32x4 acc[4][4] = {};
  for (int k0 = 0; k0 < K; k0 += 32) {
    __syncthreads();
    gld_lds16(&A[(row0 + rw0) * K + k0 + q0], &Al[tid * 8]);
    gld_lds16(&A[(row0 + rw0 + 64) * K + k0 + q0], &Al[2048 + tid * 8]);
    gld_lds16(&Bt[(col0 + rw0) * K + k0 + q0], &Bl[tid * 8]);
    gld_lds16(&Bt[(col0 + rw0 + 64) * K + k0 + q0], &Bl[2048 + tid * 8]);
    __syncthreads();
    bf16x8 af[4], bfr[4];
#pragma unroll
    for (int m = 0; m < 4; ++m) af[m] = *(const bf16x8*)&Al[(wr * 64 + m * 16 + r) * 32 + kg * 8];
#pragma unroll
    for (int n = 0; n < 4; ++n) bfr[n] = *(const bf16x8*)&Bl[(wc * 64 + n * 16 + r) * 32 + kg * 8];
#pragma unroll
    for (int m = 0; m < 4; ++m)
#pragma unroll
      for (int n = 0; n < 4; ++n)
        acc[m][n] = __builtin_amdgcn_mfma_f32_16x16x32_bf16(af[m], bfr[n], acc[m][n], 0, 0, 0);
  }
  const int rbase = wr * 64 + (lane >> 4) * 4;
  const int cbase = wc * 64 + (lane & 15);
#pragma unroll
  for (int m = 0; m < 4; ++m)
#pragma unroll
    for (int n = 0; n < 4; ++n)
#pragma unroll
      for (int j = 0; j < 4; ++j)
        C[(row0 + rbase + m * 16 + j) * N + col0 + cbase + n * 16] = acc[m][n][j];
}

// ---------------- v GEMM: A=xn[32768,1024] @ Wv^T; dual epilogue: origv f32 + vbn ----
__global__ __launch_bounds__(256) void gemm_v_kernel(const unsigned short* __restrict__ A,
                                                     const unsigned short* __restrict__ BtV,
                                                     unsigned short* __restrict__ vbn,
                                                     float* __restrict__ origv) {
  __shared__ __align__(16) unsigned short Al[4096];
  __shared__ __align__(16) unsigned short Bl[4096];
  const int tid = threadIdx.x;
  const int lane = tid & 63, wid = tid >> 6;
  const int wr = wid >> 1, wc = wid & 1;
  const int r = lane & 15, kg = lane >> 4;
  const int rw0 = tid >> 2, q0 = (tid & 3) * 8;
  const size_t row0 = (size_t)blockIdx.y * 128, col0 = (size_t)blockIdx.x * 128;
  const int K = 1024;
  f32x4 acc[4][4] = {};
  for (int k0 = 0; k0 < K; k0 += 32) {
    __syncthreads();
    gld_lds16(&A[(row0 + rw0) * K + k0 + q0], &Al[tid * 8]);
    gld_lds16(&A[(row0 + rw0 + 64) * K + k0 + q0], &Al[2048 + tid * 8]);
    gld_lds16(&BtV[(col0 + rw0) * K + k0 + q0], &Bl[tid * 8]);
    gld_lds16(&BtV[(col0 + rw0 + 64) * K + k0 + q0], &Bl[2048 + tid * 8]);
    __syncthreads();
    bf16x8 af[4], bfr[4];
#pragma unroll
    for (int m = 0; m < 4; ++m) af[m] = *(const bf16x8*)&Al[(wr * 64 + m * 16 + r) * 32 + kg * 8];
#pragma unroll
    for (int n = 0; n < 4; ++n) bfr[n] = *(const bf16x8*)&Bl[(wc * 64 + n * 16 + r) * 32 + kg * 8];
#pragma unroll
    for (int m = 0; m < 4; ++m)
#pragma unroll
      for (int n = 0; n < 4; ++n)
        acc[m][n] = __builtin_amdgcn_mfma_f32_16x16x32_bf16(af[m], bfr[n], acc[m][n], 0, 0, 0);
  }
  const int rbase = wr * 64 + (lane >> 4) * 4;
  const int cbase = wc * 64 + (lane & 15);
  const int b = (int)(row0 >> 13);
  const int nn0 = (int)(row0 & 8191) + rbase;
#pragma unroll
  for (int m = 0; m < 4; ++m)
#pragma unroll
    for (int n = 0; n < 4; ++n) {
      const int hd = (int)col0 + cbase + n * 16;
      float4 o4;
      o4.x = acc[m][n][0]; o4.y = acc[m][n][1]; o4.z = acc[m][n][2]; o4.w = acc[m][n][3];
      *(float4*)&origv[((size_t)b * 1024 + hd) * 8192 + nn0 + m * 16] = o4;
#pragma unroll
      for (int j = 0; j < 4; ++j)
        vbn[(row0 + rbase + m * 16 + j) * 1024 + hd] = f2bf(acc[m][n][j]);
    }
}

// ---------------- sim + softmax per (b,h): MFMA 64x64 over K=1024 + norms ------------
// sim_raw[d][e] = sum_i UTt_b[h64+d][i] * wqkvT[1024+h64+e][i]
// qn2[d] = row-dot(UTt_b[h64+d], wqkvT[h64+d]); kn2[e] analog on k rows.
__global__ __launch_bounds__(256) void sim_softmax_kernel(const unsigned short* __restrict__ wqkvT,
                                                          const unsigned short* __restrict__ UTt,
                                                          const float* __restrict__ temperature,
                                                          float* __restrict__ attn) {
  __shared__ __align__(16) unsigned short Aql[64 * 128];
  __shared__ __align__(16) unsigned short Bkl[64 * 128];
  __shared__ float qknl[2][64];
  const int bh = blockIdx.x;
  const int b = bh >> 4, h = bh & 15;
  const int t = threadIdx.x;
  const int lane = t & 63, w = t >> 6;
  const unsigned short* UTtb = UTt + ((size_t)b << 21);
  // phase 0: norms (threads 0..127)
  if (t < 128) {
    const int sel = t >> 6, dd = t & 63;
    const size_t roff = (size_t)(sel * 1024 + h * 64 + dd) * 1024;
    const unsigned short* pa = UTtb + roff;
    const unsigned short* pb = wqkvT + roff;
    float nv = 0.f;
    for (int i = 0; i < 1024; i += 8) {
      const u16x8 va = *(const u16x8*)&pa[i];
      const u16x8 vb = *(const u16x8*)&pb[i];
#pragma unroll
      for (int j = 0; j < 8; ++j) nv += bf2f(va[j]) * bf2f(vb[j]);
    }
    qknl[sel][dd] = fmaxf(sqrtf(nv), 1e-12f);
  }
  // phase 1: sim MFMA. wave w owns output rows w*16..w*16+15.
  const unsigned short* AqG = UTtb + (size_t)(h * 64) * 1024;
  const unsigned short* BkG = wqkvT + (size_t)(1024 + h * 64) * 1024;
  const int r = lane & 15, kg = lane >> 4;
  const int srow = t >> 4, scol = (t & 15) * 8;
  f32x4 acc[4] = {};
  for (int k0 = 0; k0 < 1024; k0 += 128) {
    __syncthreads();
#pragma unroll
    for (int c = 0; c < 4; ++c) {
      gld_lds16(&AqG[(size_t)(c * 16 + srow) * 1024 + k0 + scol], &Aql[c * 2048 + t * 8]);
      gld_lds16(&BkG[(size_t)(c * 16 + srow) * 1024 + k0 + scol], &Bkl[c * 2048 + t * 8]);
    }
    __syncthreads();
#pragma unroll
    for (int kk = 0; kk < 128; kk += 32) {
      const bf16x8 af = *(const bf16x8*)&Aql[(w * 16 + r) * 128 + kk + kg * 8];
#pragma unroll
      for (int n = 0; n < 4; ++n) {
        const bf16x8 bfr = *(const bf16x8*)&Bkl[(n * 16 + r) * 128 + kk + kg * 8];
        acc[n] = __builtin_amdgcn_mfma_f32_16x16x32_bf16(af, bfr, acc[n], 0, 0, 0);
      }
    }
  }
  // epilogue: scale, normalize, softmax over e (16-lane group + 4 regs)
  const float sc = 8.f * __expf(temperature[h]);
  const int colq = lane & 15, rq = lane >> 4;
#pragma unroll
  for (int j = 0; j < 4; ++j) {
    const int d = w * 16 + rq * 4 + j;
    const float qd = qknl[0][d];
    float sv[4];
#pragma unroll
    for (int n = 0; n < 4; ++n) sv[n] = acc[n][j] * sc / (qd * qknl[1][n * 16 + colq]);
    float mj = fmaxf(fmaxf(sv[0], sv[1]), fmaxf(sv[2], sv[3]));
    for (int msk = 1; msk < 16; msk <<= 1) mj = fmaxf(mj, __shfl_xor(mj, msk));
    float p[4], sum = 0.f;
#pragma unroll
    for (int n = 0; n < 4; ++n) { p[n] = __expf(sv[n] - mj); sum += p[n]; }
    for (int msk = 1; msk < 16; msk <<= 1) sum += __shfl_xor(sum, msk);
    const float inv = 1.f / sum;
#pragma unroll
    for (int n = 0; n < 4; ++n)
      attn[(size_t)bh * 4096 + d * 64 + n * 16 + colq] = p[n] * inv;
  }
}

// ---------------- W2T[b][c][h64+e] = sum_d attn[bh][d][e] * w_out[h64+d][c] ----------
__global__ __launch_bounds__(256) void w2t_kernel(const float* __restrict__ attn,
                                                  const float* __restrict__ w_out,
                                                  unsigned short* __restrict__ W2T) {
  __shared__ float al[64][64];
  __shared__ float wl[64][64];
  const int bh = blockIdx.y;
  const int b = bh >> 4, h = bh & 15;
  const int c0 = blockIdx.x * 256;
  const int t = threadIdx.x, e = t & 63, g = t >> 6;
  const int dr = t >> 2, q4 = (t & 3) * 16;
#pragma unroll
  for (int j = 0; j < 16; j += 4)
    *(float4*)&al[dr][q4 + j] = *(const float4*)&attn[(size_t)bh * 4096 + dr * 64 + q4 + j];
  for (int cb = 0; cb < 4; ++cb) {
    __syncthreads();
#pragma unroll
    for (int j = 0; j < 16; j += 4)
      *(float4*)&wl[dr][q4 + j] = *(const float4*)&w_out[(size_t)(h * 64 + dr) * 1024 + c0 + cb * 64 + q4 + j];
    __syncthreads();
#pragma unroll
    for (int i = 0; i < 16; ++i) {
      const int cc = g * 16 + i;
      float s = 0.f;
#pragma unroll 8
      for (int d = 0; d < 64; ++d) s += al[d][e] * wl[d][cc];
      W2T[((size_t)b << 20) + (size_t)(c0 + cb * 64 + cc) * 1024 + h * 64 + e] = f2bf(s);
    }
  }
}

extern "C" void kernel_launch(void* const* d_in, const int* in_sizes, int n_in,
                              void* d_out, int out_size, void* d_ws, size_t ws_size,
                              hipStream_t stream) {
  const float* x     = (const float*)d_in[0];
  const float* gamma = (const float*)d_in[1];
  const float* w_qkv = (const float*)d_in[2];
  const float* temp  = (const float*)d_in[3];
  const float* w_out = (const float*)d_in[4];
  char* ws = (char*)d_ws;
  unsigned short* wqkvT = (unsigned short*)(ws);                 // [3072][1024] bf16, 6.29 MB
  unsigned short* xn    = (unsigned short*)(ws + 6291456);       // [32768][1024] bf16, 67 MB
  unsigned short* xnT   = (unsigned short*)(ws + 73400320);      // [1024][32768] bf16, 67 MB
  unsigned short* vbn   = xnT;                                   // reuse after Gram
  unsigned short* Gp    = (unsigned short*)(ws + 140509184);     // [16][1024][1024] bf16, 33.5 MB
  unsigned short* G     = (unsigned short*)(ws + 174063616);     // [4][1024][1024] bf16, 8.4 MB
  unsigned short* UTt   = (unsigned short*)(ws + 182452224);     // [4][2048][1024] bf16, 16.8 MB
  float* attn           = (float*)(ws + 199229440);              // [64][64][64] f32, 1 MB
  unsigned short* W2T   = (unsigned short*)(ws + 200278016);     // [4][1024][1024] bf16 (end 208.7 MB)
  float* outp  = (float*)d_out;                                  // out: [4,8192,1024] f32
  float* origv = outp + (size_t)33554432;                        // orig_v: [4,16,64,8192] f32

  transpose_cast_kernel<<<dim3(96, 32), 256, 0, stream>>>(w_qkv, wqkvT, 1024, 3072);
  rmsnorm_kernel<<<32768, 256, 0, stream>>>(x, gamma, xn);
  transpose_bf16_kernel<<<dim3(32, 1024), 256, 0, stream>>>(xn, xnT, 32768, 1024);
  gemm_gram_kernel<<<dim3(8, 8, 16), 256, 0, stream>>>(xnT, Gp);
  greduce_kernel<<<dim3(16, 16, 4), 256, 0, stream>>>(Gp, G);
  // UTt[b] = wqkvT[0:2048] @ G_b^T  (G symmetric) : [2048][1024] per b
  gemm_bt_batch_bf16<<<dim3(8, 16, 4), 256, 0, stream>>>(wqkvT, G, UTt, 1024, 1024,
                                                         0LL, 1LL << 20, 1LL << 21);
  gemm_v_kernel<<<dim3(8, 256), 256, 0, stream>>>(xn, wqkvT + (size_t)2048 * 1024, vbn, origv);
  sim_softmax_kernel<<<64, 256, 0, stream>>>(wqkvT, UTt, temp, attn);
  w2t_kernel<<<dim3(4, 64), 256, 0, stream>>>(attn, w_out, W2T);
  // out[b] = vbn_b @ W2T_b^T : [8192][1024] per b
  gemm_bt_batch_f32<<<dim3(8, 64, 4), 256, 0, stream>>>(vbn, W2T, outp, 1024, 1024,
                                                        8388608LL, 1LL << 20, 8388608LL);
}

// Round 7
// 550.867 us; speedup vs baseline: 1.4647x; 1.0309x over previous
//
#include <hip/hip_runtime.h>
#include <hip/hip_bf16.h>

#define DEVI __device__ __forceinline__

using bf16x8 = __attribute__((ext_vector_type(8))) __bf16;
using f32x4  = __attribute__((ext_vector_type(4))) float;
using u16x8  = __attribute__((ext_vector_type(8))) unsigned short;

DEVI unsigned short f2bf(float f) {
  unsigned int u = __float_as_uint(f);
  u = (u + 0x7FFFu + ((u >> 16) & 1u)) >> 16;
  return (unsigned short)u;
}
DEVI float bf2f(unsigned short s) { return __uint_as_float(((unsigned int)s) << 16); }

// async global->LDS, 16B per lane; LDS dest must be wave-uniform-base + lane*16
DEVI void gld_lds16(const unsigned short* g, unsigned short* l) {
  __builtin_amdgcn_global_load_lds(
      (const __attribute__((address_space(1))) void*)g,
      (__attribute__((address_space(3))) void*)l, 16, 0, 0);
}

// ---------------- transpose + cast f32 -> bf16 : out[C][R] = in[R][C] ----------------
__global__ __launch_bounds__(256) void transpose_cast_kernel(const float* __restrict__ in,
                                                             unsigned short* __restrict__ out,
                                                             int R, int C) {
  __shared__ float tile[32][33];
  const int c0 = blockIdx.x * 32, r0 = blockIdx.y * 32;
  const int tx = threadIdx.x & 31, ty = threadIdx.x >> 5;
  for (int rr = ty; rr < 32; rr += 8)
    tile[rr][tx] = in[(size_t)(r0 + rr) * C + c0 + tx];
  __syncthreads();
  for (int cc = ty; cc < 32; cc += 8)
    out[(size_t)(c0 + cc) * R + r0 + tx] = f2bf(tile[tx][cc]);
}

// ---------------- cast v-weights, no transpose: Wv_nt[k][he] = bf16(w_qkv[k][2048+he])
__global__ __launch_bounds__(256) void castv_kernel(const float* __restrict__ w_qkv,
                                                    unsigned short* __restrict__ Wv_nt) {
  const int i = blockIdx.x * 256 + threadIdx.x;     // 0..262143
  const int k = i >> 8, he4 = (i & 255) * 4;
  const float4 v = *(const float4*)&w_qkv[(size_t)k * 3072 + 2048 + he4];
  ushort4 o;
  o.x = f2bf(v.x); o.y = f2bf(v.y); o.z = f2bf(v.z); o.w = f2bf(v.w);
  *(ushort4*)&Wv_nt[(size_t)k * 1024 + he4] = o;
}

// ---------------- transpose bf16 -> bf16 : out[C][R] = in[R][C] ----------------------
__global__ __launch_bounds__(256) void transpose_bf16_kernel(const unsigned short* __restrict__ in,
                                                             unsigned short* __restrict__ out,
                                                             int R, int C) {
  __shared__ unsigned short tile[32][33];
  const int c0 = blockIdx.x * 32, r0 = blockIdx.y * 32;
  const int tx = threadIdx.x & 31, ty = threadIdx.x >> 5;
  for (int rr = ty; rr < 32; rr += 8)
    tile[rr][tx] = in[(size_t)(r0 + rr) * C + c0 + tx];
  __syncthreads();
  for (int cc = ty; cc < 32; cc += 8)
    out[(size_t)(c0 + cc) * R + r0 + tx] = tile[tx][cc];
}

// ---------------- RMSNorm: xn = x / max(||x||,eps) * sqrt(1024) * gamma, bf16 out ----
__global__ __launch_bounds__(256) void rmsnorm_kernel(const float* __restrict__ x,
                                                      const float* __restrict__ gamma,
                                                      unsigned short* __restrict__ xn) {
  __shared__ float wsum[4];
  const int row = blockIdx.x;
  const int t = threadIdx.x;
  const float4 v = *(const float4*)&x[(size_t)row * 1024 + t * 4];
  float s = v.x * v.x + v.y * v.y + v.z * v.z + v.w * v.w;
  for (int off = 32; off; off >>= 1) s += __shfl_down(s, off);
  if ((t & 63) == 0) wsum[t >> 6] = s;
  __syncthreads();
  const float tot = wsum[0] + wsum[1] + wsum[2] + wsum[3];
  const float scale = 32.0f / fmaxf(sqrtf(tot), 1e-12f);
  const float4 g = *(const float4*)&gamma[t * 4];
  ushort4 o;
  o.x = f2bf(v.x * scale * g.x);
  o.y = f2bf(v.y * scale * g.y);
  o.z = f2bf(v.z * scale * g.z);
  o.w = f2bf(v.w * scale * g.w);
  *(ushort4*)&xn[(size_t)row * 1024 + t * 4] = o;
}

// ---------------- Gram: Gp[z] = xnT_b[:, ksplit] @ xnT_b[:, ksplit]^T (lower tiles) --
__global__ __launch_bounds__(256) void gemm_gram_kernel(const unsigned short* __restrict__ xnT,
                                                        unsigned short* __restrict__ Gp) {
  if (blockIdx.x > blockIdx.y) return;  // lower-triangle 128-tiles only
  __shared__ __align__(16) unsigned short Al[4096];
  __shared__ __align__(16) unsigned short Bl[4096];
  const int tid = threadIdx.x;
  const int lane = tid & 63, wid = tid >> 6;
  const int wr = wid >> 1, wc = wid & 1;
  const int r = lane & 15, kg = lane >> 4;
  const int rw0 = tid >> 2, q0 = (tid & 3) * 8;
  const size_t row0 = (size_t)blockIdx.y * 128, col0 = (size_t)blockIdx.x * 128;
  const int z = blockIdx.z;
  const size_t koff = (size_t)(z >> 2) * 8192 + (size_t)(z & 3) * 2048;
  f32x4 acc[4][4] = {};
  for (int k0 = 0; k0 < 2048; k0 += 32) {
    __syncthreads();
    gld_lds16(&xnT[(row0 + rw0) * 32768 + koff + k0 + q0], &Al[tid * 8]);
    gld_lds16(&xnT[(row0 + rw0 + 64) * 32768 + koff + k0 + q0], &Al[2048 + tid * 8]);
    gld_lds16(&xnT[(col0 + rw0) * 32768 + koff + k0 + q0], &Bl[tid * 8]);
    gld_lds16(&xnT[(col0 + rw0 + 64) * 32768 + koff + k0 + q0], &Bl[2048 + tid * 8]);
    __syncthreads();
    bf16x8 af[4], bfr[4];
#pragma unroll
    for (int m = 0; m < 4; ++m) af[m] = *(const bf16x8*)&Al[(wr * 64 + m * 16 + r) * 32 + kg * 8];
#pragma unroll
    for (int n = 0; n < 4; ++n) bfr[n] = *(const bf16x8*)&Bl[(wc * 64 + n * 16 + r) * 32 + kg * 8];
#pragma unroll
    for (int m = 0; m < 4; ++m)
#pragma unroll
      for (int n = 0; n < 4; ++n)
        acc[m][n] = __builtin_amdgcn_mfma_f32_16x16x32_bf16(af[m], bfr[n], acc[m][n], 0, 0, 0);
  }
  unsigned short* C = Gp + ((size_t)z << 20);
  const int rbase = wr * 64 + (lane >> 4) * 4;
  const int cbase = wc * 64 + (lane & 15);
#pragma unroll
  for (int m = 0; m < 4; ++m)
#pragma unroll
    for (int n = 0; n < 4; ++n)
#pragma unroll
      for (int j = 0; j < 4; ++j)
        C[(row0 + rbase + m * 16 + j) * 1024 + col0 + cbase + n * 16] = f2bf(acc[m][n][j]);
}

// ---------------- reduce split-K partials + mirror to full symmetric G (bf16) --------
__global__ __launch_bounds__(256) void greduce_kernel(const unsigned short* __restrict__ Gp,
                                                      unsigned short* __restrict__ G) {
  const int tj = blockIdx.x, ti = blockIdx.y, b = blockIdx.z;
  if ((tj >> 1) > (ti >> 1)) return;  // source 128-tile not computed
  __shared__ float lds[64][65];
  const int t = threadIdx.x;
  const int r = t >> 2, c0 = (t & 3) * 16;
  const size_t idx = (size_t)(ti * 64 + r) * 1024 + tj * 64 + c0;
  float v[16];
#pragma unroll
  for (int j = 0; j < 16; ++j) v[j] = 0.f;
  for (int s = 0; s < 4; ++s) {
    const unsigned short* p = Gp + ((size_t)(b * 4 + s) << 20) + idx;
#pragma unroll
    for (int j = 0; j < 16; ++j) v[j] += bf2f(p[j]);
  }
  unsigned short* Gb = G + ((size_t)b << 20);
  __attribute__((aligned(16))) unsigned short buf[16];
#pragma unroll
  for (int j = 0; j < 16; ++j) buf[j] = f2bf(v[j]);
  { int4* dst = (int4*)&Gb[idx]; const int4* src = (const int4*)buf; dst[0] = src[0]; dst[1] = src[1]; }
  if ((ti >> 1) != (tj >> 1)) {  // mirror to upper region (block-uniform branch)
#pragma unroll
    for (int j = 0; j < 16; ++j) lds[r][c0 + j] = v[j];
    __syncthreads();
    const int x = t >> 2, y0 = (t & 3) * 16;
#pragma unroll
    for (int j = 0; j < 16; ++j) buf[j] = f2bf(lds[y0 + j][x]);
    int4* dst = (int4*)&Gb[(size_t)(tj * 64 + x) * 1024 + ti * 64 + y0];
    const int4* src = (const int4*)buf;
    dst[0] = src[0]; dst[1] = src[1];
  }
}

// ---------------- batched bf16 GEMM: C[M,N] = A @ Bt^T, bf16 out ---------------------
__global__ __launch_bounds__(256) void gemm_bt_batch_bf16(const unsigned short* __restrict__ A,
                                                          const unsigned short* __restrict__ Bt,
                                                          unsigned short* __restrict__ C,
                                                          int N, int K,
                                                          long long aStr, long long bStr, long long cStr) {
  __shared__ __align__(16) unsigned short Al[4096];
  __shared__ __align__(16) unsigned short Bl[4096];
  A += (size_t)blockIdx.z * aStr; Bt += (size_t)blockIdx.z * bStr; C += (size_t)blockIdx.z * cStr;
  const int tid = threadIdx.x;
  const int lane = tid & 63, wid = tid >> 6;
  const int wr = wid >> 1, wc = wid & 1;
  const int r = lane & 15, kg = lane >> 4;
  const int rw0 = tid >> 2, q0 = (tid & 3) * 8;
  const size_t row0 = (size_t)blockIdx.y * 128, col0 = (size_t)blockIdx.x * 128;
  f32x4 acc[4][4] = {};
  for (int k0 = 0; k0 < K; k0 += 32) {
    __syncthreads();
    gld_lds16(&A[(row0 + rw0) * K + k0 + q0], &Al[tid * 8]);
    gld_lds16(&A[(row0 + rw0 + 64) * K + k0 + q0], &Al[2048 + tid * 8]);
    gld_lds16(&Bt[(col0 + rw0) * K + k0 + q0], &Bl[tid * 8]);
    gld_lds16(&Bt[(col0 + rw0 + 64) * K + k0 + q0], &Bl[2048 + tid * 8]);
    __syncthreads();
    bf16x8 af[4], bfr[4];
#pragma unroll
    for (int m = 0; m < 4; ++m) af[m] = *(const bf16x8*)&Al[(wr * 64 + m * 16 + r) * 32 + kg * 8];
#pragma unroll
    for (int n = 0; n < 4; ++n) bfr[n] = *(const bf16x8*)&Bl[(wc * 64 + n * 16 + r) * 32 + kg * 8];
#pragma unroll
    for (int m = 0; m < 4; ++m)
#pragma unroll
      for (int n = 0; n < 4; ++n)
        acc[m][n] = __builtin_amdgcn_mfma_f32_16x16x32_bf16(af[m], bfr[n], acc[m][n], 0, 0, 0);
  }
  const int rbase = wr * 64 + (lane >> 4) * 4;
  const int cbase = wc * 64 + (lane & 15);
#pragma unroll
  for (int m = 0; m < 4; ++m)
#pragma unroll
    for (int n = 0; n < 4; ++n)
#pragma unroll
      for (int j = 0; j < 4; ++j)
        C[(row0 + rbase + m * 16 + j) * N + col0 + cbase + n * 16] = f2bf(acc[m][n][j]);
}

// ---------------- fused output GEMM: A=xn[32768,1024]; col panels 0..7 -> v/origv, ---
// col panels 8..15 -> out = xn @ Wfold_b. XCD-chunked block swizzle (nwg=4096).
__global__ __launch_bounds__(256) void gemm_vout_kernel(const unsigned short* __restrict__ A,
                                                        const unsigned short* __restrict__ BtV,
                                                        const unsigned short* __restrict__ WfoldT,
                                                        float* __restrict__ origv,
                                                        float* __restrict__ outp) {
  __shared__ __align__(16) unsigned short Al[4096];
  __shared__ __align__(16) unsigned short Bl[4096];
  const int flat = blockIdx.x;
  const int s = (flat & 7) * 512 + (flat >> 3);   // bijective: 4096 % 8 == 0
  const int cb = s & 15, rb = s >> 4;
  const size_t row0 = (size_t)rb * 128;
  const int b = rb >> 6;
  const unsigned short* Bt = (cb < 8)
      ? BtV + (size_t)cb * 128 * 1024
      : WfoldT + ((size_t)b << 20) + (size_t)(cb - 8) * 128 * 1024;
  const int tid = threadIdx.x;
  const int lane = tid & 63, wid = tid >> 6;
  const int wr = wid >> 1, wc = wid & 1;
  const int r = lane & 15, kg = lane >> 4;
  const int rw0 = tid >> 2, q0 = (tid & 3) * 8;
  const int K = 1024;
  f32x4 acc[4][4] = {};
  for (int k0 = 0; k0 < K; k0 += 32) {
    __syncthreads();
    gld_lds16(&A[(row0 + rw0) * K + k0 + q0], &Al[tid * 8]);
    gld_lds16(&A[(row0 + rw0 + 64) * K + k0 + q0], &Al[2048 + tid * 8]);
    gld_lds16(&Bt[(size_t)rw0 * K + k0 + q0], &Bl[tid * 8]);
    gld_lds16(&Bt[(size_t)(rw0 + 64) * K + k0 + q0], &Bl[2048 + tid * 8]);
    __syncthreads();
    bf16x8 af[4], bfr[4];
#pragma unroll
    for (int m = 0; m < 4; ++m) af[m] = *(const bf16x8*)&Al[(wr * 64 + m * 16 + r) * 32 + kg * 8];
#pragma unroll
    for (int n = 0; n < 4; ++n) bfr[n] = *(const bf16x8*)&Bl[(wc * 64 + n * 16 + r) * 32 + kg * 8];
#pragma unroll
    for (int m = 0; m < 4; ++m)
#pragma unroll
      for (int n = 0; n < 4; ++n)
        acc[m][n] = __builtin_amdgcn_mfma_f32_16x16x32_bf16(af[m], bfr[n], acc[m][n], 0, 0, 0);
  }
  const int rbase = wr * 64 + (lane >> 4) * 4;
  const int cbase = wc * 64 + (lane & 15);
  if (cb < 8) {  // v panel: origv[b][hd][n] f32, transposed epilogue
    const int nn0 = (int)(row0 & 8191) + rbase;
#pragma unroll
    for (int m = 0; m < 4; ++m)
#pragma unroll
      for (int n = 0; n < 4; ++n) {
        const int hd = cb * 128 + cbase + n * 16;
        float4 o4;
        o4.x = acc[m][n][0]; o4.y = acc[m][n][1]; o4.z = acc[m][n][2]; o4.w = acc[m][n][3];
        *(float4*)&origv[((size_t)b * 1024 + hd) * 8192 + nn0 + m * 16] = o4;
      }
  } else {  // out panel: out[row][c] f32 row-major
    const size_t col0 = (size_t)(cb - 8) * 128;
#pragma unroll
    for (int m = 0; m < 4; ++m)
#pragma unroll
      for (int n = 0; n < 4; ++n)
#pragma unroll
        for (int j = 0; j < 4; ++j)
          outp[(row0 + rbase + m * 16 + j) * 1024 + col0 + cbase + n * 16] = acc[m][n][j];
  }
}

// ---------------- norms: qkn2[b*2048+row] = dot(UTt_b[row], wqkvT[row]) --------------
__global__ __launch_bounds__(256) void norms_kernel(const unsigned short* __restrict__ UTt,
                                                    const unsigned short* __restrict__ wqkvT,
                                                    float* __restrict__ qkn2) {
  const int t = threadIdx.x;
  const int rloc = t >> 4, lane16 = t & 15;
  const int row = blockIdx.x * 16 + rloc;   // 0..8191
  const int b = row >> 11, r2 = row & 2047;
  const unsigned short* pa = UTt + ((size_t)b << 21) + (size_t)r2 * 1024 + lane16 * 64;
  const unsigned short* pb = wqkvT + (size_t)r2 * 1024 + lane16 * 64;
  float s = 0.f;
  for (int i = 0; i < 64; i += 8) {
    const u16x8 va = *(const u16x8*)&pa[i];
    const u16x8 vb = *(const u16x8*)&pb[i];
#pragma unroll
    for (int j = 0; j < 8; ++j) s += bf2f(va[j]) * bf2f(vb[j]);
  }
  for (int off = 8; off; off >>= 1) s += __shfl_down(s, off, 16);
  if (lane16 == 0) qkn2[row] = s;
}

// ---------------- sim + softmax per (b,h): MFMA 64x64 over K=1024 --------------------
__global__ __launch_bounds__(256) void sim_softmax_kernel(const unsigned short* __restrict__ wqkvT,
                                                          const unsigned short* __restrict__ UTt,
                                                          const float* __restrict__ qkn2,
                                                          const float* __restrict__ temperature,
                                                          float* __restrict__ attn) {
  __shared__ __align__(16) unsigned short Aql[64 * 128];
  __shared__ __align__(16) unsigned short Bkl[64 * 128];
  __shared__ float qknl[2][64];
  const int bh = blockIdx.x;
  const int b = bh >> 4, h = bh & 15;
  const int t = threadIdx.x;
  const int lane = t & 63, w = t >> 6;
  const unsigned short* UTtb = UTt + ((size_t)b << 21);
  if (t < 128) {
    const int sel = t >> 6, dd = t & 63;
    qknl[sel][dd] = fmaxf(sqrtf(qkn2[b * 2048 + sel * 1024 + h * 64 + dd]), 1e-12f);
  }
  const unsigned short* AqG = UTtb + (size_t)(h * 64) * 1024;
  const unsigned short* BkG = wqkvT + (size_t)(1024 + h * 64) * 1024;
  const int r = lane & 15, kg = lane >> 4;
  const int srow = t >> 4, scol = (t & 15) * 8;
  f32x4 acc[4] = {};
  for (int k0 = 0; k0 < 1024; k0 += 128) {
    __syncthreads();
#pragma unroll
    for (int c = 0; c < 4; ++c) {
      gld_lds16(&AqG[(size_t)(c * 16 + srow) * 1024 + k0 + scol], &Aql[c * 2048 + t * 8]);
      gld_lds16(&BkG[(size_t)(c * 16 + srow) * 1024 + k0 + scol], &Bkl[c * 2048 + t * 8]);
    }
    __syncthreads();
#pragma unroll
    for (int kk = 0; kk < 128; kk += 32) {
      const bf16x8 af = *(const bf16x8*)&Aql[(w * 16 + r) * 128 + kk + kg * 8];
#pragma unroll
      for (int n = 0; n < 4; ++n) {
        const bf16x8 bfr = *(const bf16x8*)&Bkl[(n * 16 + r) * 128 + kk + kg * 8];
        acc[n] = __builtin_amdgcn_mfma_f32_16x16x32_bf16(af, bfr, acc[n], 0, 0, 0);
      }
    }
  }
  const float sc = 8.f * __expf(temperature[h]);
  const int colq = lane & 15, rq = lane >> 4;
#pragma unroll
  for (int j = 0; j < 4; ++j) {
    const int d = w * 16 + rq * 4 + j;
    const float qd = qknl[0][d];
    float sv[4];
#pragma unroll
    for (int n = 0; n < 4; ++n) sv[n] = acc[n][j] * sc / (qd * qknl[1][n * 16 + colq]);
    float mj = fmaxf(fmaxf(sv[0], sv[1]), fmaxf(sv[2], sv[3]));
    for (int msk = 1; msk < 16; msk <<= 1) mj = fmaxf(mj, __shfl_xor(mj, msk));
    float p[4], sum = 0.f;
#pragma unroll
    for (int n = 0; n < 4; ++n) { p[n] = __expf(sv[n] - mj); sum += p[n]; }
    for (int msk = 1; msk < 16; msk <<= 1) sum += __shfl_xor(sum, msk);
    const float inv = 1.f / sum;
#pragma unroll
    for (int n = 0; n < 4; ++n)
      attn[(size_t)bh * 4096 + d * 64 + n * 16 + colq] = p[n] * inv;
  }
}

// ---------------- W2T[b][c][h64+e] = sum_d attn[bh][d][e] * w_out[h64+d][c] ----------
__global__ __launch_bounds__(256) void w2t_kernel(const float* __restrict__ attn,
                                                  const float* __restrict__ w_out,
                                                  unsigned short* __restrict__ W2T) {
  __shared__ float al[64][64];
  __shared__ float wl[64][64];
  const int bh = blockIdx.y;
  const int b = bh >> 4, h = bh & 15;
  const int c0 = blockIdx.x * 256;
  const int t = threadIdx.x, e = t & 63, g = t >> 6;
  const int dr = t >> 2, q4 = (t & 3) * 16;
#pragma unroll
  for (int j = 0; j < 16; j += 4)
    *(float4*)&al[dr][q4 + j] = *(const float4*)&attn[(size_t)bh * 4096 + dr * 64 + q4 + j];
  for (int cb = 0; cb < 4; ++cb) {
    __syncthreads();
#pragma unroll
    for (int j = 0; j < 16; j += 4)
      *(float4*)&wl[dr][q4 + j] = *(const float4*)&w_out[(size_t)(h * 64 + dr) * 1024 + c0 + cb * 64 + q4 + j];
    __syncthreads();
#pragma unroll
    for (int i = 0; i < 16; ++i) {
      const int cc = g * 16 + i;
      float s = 0.f;
#pragma unroll 8
      for (int d = 0; d < 64; ++d) s += al[d][e] * wl[d][cc];
      W2T[((size_t)b << 20) + (size_t)(c0 + cb * 64 + cc) * 1024 + h * 64 + e] = f2bf(s);
    }
  }
}

extern "C" void kernel_launch(void* const* d_in, const int* in_sizes, int n_in,
                              void* d_out, int out_size, void* d_ws, size_t ws_size,
                              hipStream_t stream) {
  const float* x     = (const float*)d_in[0];
  const float* gamma = (const float*)d_in[1];
  const float* w_qkv = (const float*)d_in[2];
  const float* temp  = (const float*)d_in[3];
  const float* w_out = (const float*)d_in[4];
  char* ws = (char*)d_ws;
  unsigned short* wqkvT  = (unsigned short*)(ws);                 // [3072][1024] bf16, 6.29 MB
  unsigned short* Wv_nt  = (unsigned short*)(ws + 6291456);       // [1024][1024] bf16, 2.1 MB
  unsigned short* xn     = (unsigned short*)(ws + 8388608);       // [32768][1024] bf16, 67 MB
  unsigned short* xnT    = (unsigned short*)(ws + 75497472);      // [1024][32768] bf16, 67 MB
  unsigned short* Gp     = (unsigned short*)(ws + 142606336);     // [16][1024][1024] bf16, 33.5 MB
  unsigned short* G      = (unsigned short*)(ws + 176160768);     // [4][1024][1024] bf16, 8.4 MB
  unsigned short* UTt    = (unsigned short*)(ws + 184549376);     // [4][2048][1024] bf16, 16.8 MB
  float* qkn2            = (float*)(ws + 201326592);              // [4][2048] f32, 32 KB
  float* attn            = (float*)(ws + 201359360);              // [64][64][64] f32, 1 MB
  unsigned short* W2T    = (unsigned short*)(ws + 202407936);     // [4][1024][1024] bf16, 8.4 MB
  unsigned short* WfoldT = (unsigned short*)(ws + 210796544);     // [4][1024][1024] bf16 (end 219.2 MB)
  float* outp  = (float*)d_out;                                   // out: [4,8192,1024] f32
  float* origv = outp + (size_t)33554432;                         // orig_v: [4,16,64,8192] f32

  transpose_cast_kernel<<<dim3(96, 32), 256, 0, stream>>>(w_qkv, wqkvT, 1024, 3072);
  castv_kernel<<<1024, 256, 0, stream>>>(w_qkv, Wv_nt);
  rmsnorm_kernel<<<32768, 256, 0, stream>>>(x, gamma, xn);
  transpose_bf16_kernel<<<dim3(32, 1024), 256, 0, stream>>>(xn, xnT, 32768, 1024);
  gemm_gram_kernel<<<dim3(8, 8, 16), 256, 0, stream>>>(xnT, Gp);
  greduce_kernel<<<dim3(16, 16, 4), 256, 0, stream>>>(Gp, G);
  // UTt[b] = wqkvT[0:2048] @ G_b^T  (G symmetric) : [2048][1024] per b
  gemm_bt_batch_bf16<<<dim3(8, 16, 4), 256, 0, stream>>>(wqkvT, G, UTt, 1024, 1024,
                                                         0LL, 1LL << 20, 1LL << 21);
  norms_kernel<<<512, 256, 0, stream>>>(UTt, wqkvT, qkn2);
  sim_softmax_kernel<<<64, 256, 0, stream>>>(wqkvT, UTt, qkn2, temp, attn);
  w2t_kernel<<<dim3(4, 64), 256, 0, stream>>>(attn, w_out, W2T);
  // WfoldT_b[c][k] = sum_he W2T_b[c][he] * Wv_nt[k][he]
  gemm_bt_batch_bf16<<<dim3(8, 8, 4), 256, 0, stream>>>(W2T, Wv_nt, WfoldT, 1024, 1024,
                                                        1LL << 20, 0LL, 1LL << 20);
  // fused: origv (cols 0..1023 of [Wv]) + out (= xn @ Wfold_b)
  gemm_vout_kernel<<<4096, 256, 0, stream>>>(xn, wqkvT + (size_t)2048 * 1024, WfoldT,
                                             origv, outp);
}

// Round 8
// 510.815 us; speedup vs baseline: 1.5795x; 1.0784x over previous
//
#include <hip/hip_runtime.h>
#include <hip/hip_bf16.h>

#define DEVI __device__ __forceinline__

using bf16x8 = __attribute__((ext_vector_type(8))) __bf16;
using f32x4  = __attribute__((ext_vector_type(4))) float;
using u16x8  = __attribute__((ext_vector_type(8))) unsigned short;

DEVI unsigned short f2bf(float f) {
  unsigned int u = __float_as_uint(f);
  u = (u + 0x7FFFu + ((u >> 16) & 1u)) >> 16;
  return (unsigned short)u;
}
DEVI float bf2f(unsigned short s) { return __uint_as_float(((unsigned int)s) << 16); }

// async global->LDS, 16B per lane; LDS dest must be wave-uniform-base + lane*16
DEVI void gld_lds16(const unsigned short* g, unsigned short* l) {
  __builtin_amdgcn_global_load_lds(
      (const __attribute__((address_space(1))) void*)g,
      (__attribute__((address_space(3))) void*)l, 16, 0, 0);
}

// ---------------- transpose + cast f32 -> bf16 : out[C][R] = in[R][C] ----------------
__global__ __launch_bounds__(256) void transpose_cast_kernel(const float* __restrict__ in,
                                                             unsigned short* __restrict__ out,
                                                             int R, int C) {
  __shared__ float tile[32][33];
  const int c0 = blockIdx.x * 32, r0 = blockIdx.y * 32;
  const int tx = threadIdx.x & 31, ty = threadIdx.x >> 5;
  for (int rr = ty; rr < 32; rr += 8)
    tile[rr][tx] = in[(size_t)(r0 + rr) * C + c0 + tx];
  __syncthreads();
  for (int cc = ty; cc < 32; cc += 8)
    out[(size_t)(c0 + cc) * R + r0 + tx] = f2bf(tile[tx][cc]);
}

// ---------------- cast v-weights, no transpose: Wv_nt[k][he] = bf16(w_qkv[k][2048+he])
__global__ __launch_bounds__(256) void castv_kernel(const float* __restrict__ w_qkv,
                                                    unsigned short* __restrict__ Wv_nt) {
  const int i = blockIdx.x * 256 + threadIdx.x;
  const int k = i >> 8, he4 = (i & 255) * 4;
  const float4 v = *(const float4*)&w_qkv[(size_t)k * 3072 + 2048 + he4];
  ushort4 o;
  o.x = f2bf(v.x); o.y = f2bf(v.y); o.z = f2bf(v.z); o.w = f2bf(v.w);
  *(ushort4*)&Wv_nt[(size_t)k * 1024 + he4] = o;
}

// ---------------- vectorized bf16 transpose: in[32768][1024] -> out[1024][32768] -----
__global__ __launch_bounds__(256) void transpose_bf16x4_kernel(const unsigned short* __restrict__ in,
                                                               unsigned short* __restrict__ out) {
  __shared__ unsigned short tile[64][68];
  const int r0 = blockIdx.x * 64;   // row in 'in'
  const int c0 = blockIdx.y * 64;   // col in 'in'
  const int t = threadIdx.x;
  const int tr = t >> 4, tc4 = (t & 15) * 4;
#pragma unroll
  for (int p = 0; p < 4; ++p) {
    const int rr = p * 16 + tr;
    *(ushort4*)&tile[rr][tc4] = *(const ushort4*)&in[(size_t)(r0 + rr) * 1024 + c0 + tc4];
  }
  __syncthreads();
#pragma unroll
  for (int p = 0; p < 4; ++p) {
    const int cc = p * 16 + tr;
    ushort4 o;
    o.x = tile[tc4 + 0][cc];
    o.y = tile[tc4 + 1][cc];
    o.z = tile[tc4 + 2][cc];
    o.w = tile[tc4 + 3][cc];
    *(ushort4*)&out[(size_t)(c0 + cc) * 32768 + r0 + tc4] = o;
  }
}

// ---------------- RMSNorm ------------------------------------------------------------
__global__ __launch_bounds__(256) void rmsnorm_kernel(const float* __restrict__ x,
                                                      const float* __restrict__ gamma,
                                                      unsigned short* __restrict__ xn) {
  __shared__ float wsum[4];
  const int row = blockIdx.x;
  const int t = threadIdx.x;
  const float4 v = *(const float4*)&x[(size_t)row * 1024 + t * 4];
  float s = v.x * v.x + v.y * v.y + v.z * v.z + v.w * v.w;
  for (int off = 32; off; off >>= 1) s += __shfl_down(s, off);
  if ((t & 63) == 0) wsum[t >> 6] = s;
  __syncthreads();
  const float tot = wsum[0] + wsum[1] + wsum[2] + wsum[3];
  const float scale = 32.0f / fmaxf(sqrtf(tot), 1e-12f);
  const float4 g = *(const float4*)&gamma[t * 4];
  ushort4 o;
  o.x = f2bf(v.x * scale * g.x);
  o.y = f2bf(v.y * scale * g.y);
  o.z = f2bf(v.z * scale * g.z);
  o.w = f2bf(v.w * scale * g.w);
  *(ushort4*)&xn[(size_t)row * 1024 + t * 4] = o;
}

// ---------------- Gram: Gp[z] = xnT_b[:, ksplit] @ xnT_b[:, ksplit]^T (lower tiles) --
__global__ __launch_bounds__(256) void gemm_gram_kernel(const unsigned short* __restrict__ xnT,
                                                        unsigned short* __restrict__ Gp) {
  if (blockIdx.x > blockIdx.y) return;
  __shared__ __align__(16) unsigned short Al[4096];
  __shared__ __align__(16) unsigned short Bl[4096];
  const int tid = threadIdx.x;
  const int lane = tid & 63, wid = tid >> 6;
  const int wr = wid >> 1, wc = wid & 1;
  const int r = lane & 15, kg = lane >> 4;
  const int rw0 = tid >> 2, q0 = (tid & 3) * 8;
  const size_t row0 = (size_t)blockIdx.y * 128, col0 = (size_t)blockIdx.x * 128;
  const int z = blockIdx.z;
  const size_t koff = (size_t)(z >> 2) * 8192 + (size_t)(z & 3) * 2048;
  f32x4 acc[4][4] = {};
  for (int k0 = 0; k0 < 2048; k0 += 32) {
    __syncthreads();
    gld_lds16(&xnT[(row0 + rw0) * 32768 + koff + k0 + q0], &Al[tid * 8]);
    gld_lds16(&xnT[(row0 + rw0 + 64) * 32768 + koff + k0 + q0], &Al[2048 + tid * 8]);
    gld_lds16(&xnT[(col0 + rw0) * 32768 + koff + k0 + q0], &Bl[tid * 8]);
    gld_lds16(&xnT[(col0 + rw0 + 64) * 32768 + koff + k0 + q0], &Bl[2048 + tid * 8]);
    __syncthreads();
    bf16x8 af[4], bfr[4];
#pragma unroll
    for (int m = 0; m < 4; ++m) af[m] = *(const bf16x8*)&Al[(wr * 64 + m * 16 + r) * 32 + kg * 8];
#pragma unroll
    for (int n = 0; n < 4; ++n) bfr[n] = *(const bf16x8*)&Bl[(wc * 64 + n * 16 + r) * 32 + kg * 8];
#pragma unroll
    for (int m = 0; m < 4; ++m)
#pragma unroll
      for (int n = 0; n < 4; ++n)
        acc[m][n] = __builtin_amdgcn_mfma_f32_16x16x32_bf16(af[m], bfr[n], acc[m][n], 0, 0, 0);
  }
  unsigned short* C = Gp + ((size_t)z << 20);
  const int rbase = wr * 64 + (lane >> 4) * 4;
  const int cbase = wc * 64 + (lane & 15);
#pragma unroll
  for (int m = 0; m < 4; ++m)
#pragma unroll
    for (int n = 0; n < 4; ++n)
#pragma unroll
      for (int j = 0; j < 4; ++j)
        C[(row0 + rbase + m * 16 + j) * 1024 + col0 + cbase + n * 16] = f2bf(acc[m][n][j]);
}

// ---------------- reduce split-K partials + mirror to full symmetric G (bf16) --------
__global__ __launch_bounds__(256) void greduce_kernel(const unsigned short* __restrict__ Gp,
                                                      unsigned short* __restrict__ G) {
  const int tj = blockIdx.x, ti = blockIdx.y, b = blockIdx.z;
  if ((tj >> 1) > (ti >> 1)) return;
  __shared__ float lds[64][65];
  const int t = threadIdx.x;
  const int r = t >> 2, c0 = (t & 3) * 16;
  const size_t idx = (size_t)(ti * 64 + r) * 1024 + tj * 64 + c0;
  float v[16];
#pragma unroll
  for (int j = 0; j < 16; ++j) v[j] = 0.f;
  for (int s = 0; s < 4; ++s) {
    const unsigned short* p = Gp + ((size_t)(b * 4 + s) << 20) + idx;
#pragma unroll
    for (int j = 0; j < 16; ++j) v[j] += bf2f(p[j]);
  }
  unsigned short* Gb = G + ((size_t)b << 20);
  __attribute__((aligned(16))) unsigned short buf[16];
#pragma unroll
  for (int j = 0; j < 16; ++j) buf[j] = f2bf(v[j]);
  { int4* dst = (int4*)&Gb[idx]; const int4* src = (const int4*)buf; dst[0] = src[0]; dst[1] = src[1]; }
  if ((ti >> 1) != (tj >> 1)) {
#pragma unroll
    for (int j = 0; j < 16; ++j) lds[r][c0 + j] = v[j];
    __syncthreads();
    const int x = t >> 2, y0 = (t & 3) * 16;
#pragma unroll
    for (int j = 0; j < 16; ++j) buf[j] = f2bf(lds[y0 + j][x]);
    int4* dst = (int4*)&Gb[(size_t)(tj * 64 + x) * 1024 + ti * 64 + y0];
    const int4* src = (const int4*)buf;
    dst[0] = src[0]; dst[1] = src[1];
  }
}

// ---------------- batched bf16 GEMM: C[M,N] = A @ Bt^T, bf16 out ---------------------
__global__ __launch_bounds__(256) void gemm_bt_batch_bf16(const unsigned short* __restrict__ A,
                                                          const unsigned short* __restrict__ Bt,
                                                          unsigned short* __restrict__ C,
                                                          int N, int K,
                                                          long long aStr, long long bStr, long long cStr) {
  __shared__ __align__(16) unsigned short Al[4096];
  __shared__ __align__(16) unsigned short Bl[4096];
  A += (size_t)blockIdx.z * aStr; Bt += (size_t)blockIdx.z * bStr; C += (size_t)blockIdx.z * cStr;
  const int tid = threadIdx.x;
  const int lane = tid & 63, wid = tid >> 6;
  const int wr = wid >> 1, wc = wid & 1;
  const int r = lane & 15, kg = lane >> 4;
  const int rw0 = tid >> 2, q0 = (tid & 3) * 8;
  const size_t row0 = (size_t)blockIdx.y * 128, col0 = (size_t)blockIdx.x * 128;
  f32x4 acc[4][4] = {};
  for (int k0 = 0; k0 < K; k0 += 32) {
    __syncthreads();
    gld_lds16(&A[(row0 + rw0) * K + k0 + q0], &Al[tid * 8]);
    gld_lds16(&A[(row0 + rw0 + 64) * K + k0 + q0], &Al[2048 + tid * 8]);
    gld_lds16(&Bt[(col0 + rw0) * K + k0 + q0], &Bl[tid * 8]);
    gld_lds16(&Bt[(col0 + rw0 + 64) * K + k0 + q0], &Bl[2048 + tid * 8]);
    __syncthreads();
    bf16x8 af[4], bfr[4];
#pragma unroll
    for (int m = 0; m < 4; ++m) af[m] = *(const bf16x8*)&Al[(wr * 64 + m * 16 + r) * 32 + kg * 8];
#pragma unroll
    for (int n = 0; n < 4; ++n) bfr[n] = *(const bf16x8*)&Bl[(wc * 64 + n * 16 + r) * 32 + kg * 8];
#pragma unroll
    for (int m = 0; m < 4; ++m)
#pragma unroll
      for (int n = 0; n < 4; ++n)
        acc[m][n] = __builtin_amdgcn_mfma_f32_16x16x32_bf16(af[m], bfr[n], acc[m][n], 0, 0, 0);
  }
  const int rbase = wr * 64 + (lane >> 4) * 4;
  const int cbase = wc * 64 + (lane & 15);
#pragma unroll
  for (int m = 0; m < 4; ++m)
#pragma unroll
    for (int n = 0; n < 4; ++n)
#pragma unroll
      for (int j = 0; j < 4; ++j)
        C[(row0 + rbase + m * 16 + j) * N + col0 + cbase + n * 16] = f2bf(acc[m][n][j]);
}

// ============== 256x256 dbuf GEMM with counted vmcnt + swizzled LDS + setprio ========
// A = xn [32768][1024]; col-tiles 0..3 -> v (origv f32 transposed), 4..7 -> out (f32).
// 8 waves (2Mx4N), BK=64, LDS 128 KiB double-buffered, per-wave output 128x64.
// LDS swizzle: logical k-slot s (16B) stored at s ^ (row&7); staged via pre-swizzled
// global source (linear LDS dest, rule #21); reads XOR the same pattern.
DEVI void stage256(const unsigned short* __restrict__ gA,
                   const unsigned short* __restrict__ gB,
                   unsigned short* lA, unsigned short* lB,
                   int k0, int w, int lane) {
  const int dr = lane >> 3;                 // row within octet
  const int ks = (lane & 7) ^ dr;           // pre-swizzled logical k-slot
  const size_t lo = (size_t)dr * 1024 + k0 + ks * 8;
#pragma unroll
  for (int i = 0; i < 4; ++i) {
    const int oct = w * 4 + i;              // 8-row octet index (0..31)
    gld_lds16(gA + (size_t)oct * 8192 + lo, lA + oct * 512 + lane * 8);
    gld_lds16(gB + (size_t)oct * 8192 + lo, lB + oct * 512 + lane * 8);
  }
}

DEVI void compute256(const unsigned short* __restrict__ lA,
                     const unsigned short* __restrict__ lB,
                     int wm, int wn, int lane, f32x4 (&acc)[8][4]) {
  const int r = lane & 15, kg = lane >> 4;
  const int r7 = r & 7;
#pragma unroll
  for (int ksl = 0; ksl < 2; ++ksl) {
    const int sA = (((ksl << 2) + kg) ^ r7) * 8;   // swizzled 16B-slot, ushort offset
    bf16x8 af[8], bfr[4];
#pragma unroll
    for (int m = 0; m < 8; ++m)
      af[m] = *(const bf16x8*)&lA[(wm * 128 + m * 16 + r) * 64 + sA];
#pragma unroll
    for (int n = 0; n < 4; ++n)
      bfr[n] = *(const bf16x8*)&lB[(wn * 64 + n * 16 + r) * 64 + sA];
#pragma unroll
    for (int m = 0; m < 8; ++m)
#pragma unroll
      for (int n = 0; n < 4; ++n)
        acc[m][n] = __builtin_amdgcn_mfma_f32_16x16x32_bf16(af[m], bfr[n], acc[m][n], 0, 0, 0);
  }
}

#define VOUT_BAR()  __builtin_amdgcn_sched_barrier(0); __builtin_amdgcn_s_barrier(); \
                    __builtin_amdgcn_sched_barrier(0)
#define VOUT_W8()   asm volatile("s_waitcnt vmcnt(8)" ::: "memory")
#define VOUT_W0()   asm volatile("s_waitcnt vmcnt(0)" ::: "memory")

__global__ __launch_bounds__(512, 2) void gemm_vout256_kernel(
    const unsigned short* __restrict__ A,       // xn [32768][1024]
    const unsigned short* __restrict__ BtV,     // v-weight rows [1024][1024]
    const unsigned short* __restrict__ WfoldT,  // [4][1024][1024]
    float* __restrict__ origv,
    float* __restrict__ outp) {
  __shared__ __align__(16) unsigned short Al[2][16384];
  __shared__ __align__(16) unsigned short Bl[2][16384];
  const int tid = threadIdx.x;
  const int lane = tid & 63;
  const int w = tid >> 6;                 // 0..7
  const int wm = w >> 2, wn = w & 3;      // 2x4 wave grid
  const int cb = blockIdx.x & 7;          // col-tile: round-robins XCDs -> B L2-resident
  const int rb = blockIdx.x >> 3;         // row-tile 0..127
  const int b = rb >> 5;                  // batch
  const unsigned short* gA = A + (size_t)rb * 256 * 1024;
  const unsigned short* gB = (cb < 4)
      ? BtV + (size_t)cb * 256 * 1024
      : WfoldT + ((size_t)b << 20) + (size_t)(cb - 4) * 256 * 1024;

  f32x4 acc[8][4] = {};
  stage256(gA, gB, Al[0], Bl[0], 0, w, lane);               // tile 0
#pragma unroll 1
  for (int tt = 0; tt < 7; ++tt) {                          // tiles 2tt, 2tt+1
    stage256(gA, gB, Al[1], Bl[1], (tt * 2 + 1) * 64, w, lane);
    VOUT_W8(); VOUT_BAR();
    __builtin_amdgcn_s_setprio(1);
    compute256(Al[0], Bl[0], wm, wn, lane, acc);
    __builtin_amdgcn_s_setprio(0);
    VOUT_BAR();
    stage256(gA, gB, Al[0], Bl[0], (tt * 2 + 2) * 64, w, lane);
    VOUT_W8(); VOUT_BAR();
    __builtin_amdgcn_s_setprio(1);
    compute256(Al[1], Bl[1], wm, wn, lane, acc);
    __builtin_amdgcn_s_setprio(0);
    VOUT_BAR();
  }
  // tiles 14, 15
  stage256(gA, gB, Al[1], Bl[1], 15 * 64, w, lane);
  VOUT_W8(); VOUT_BAR();
  __builtin_amdgcn_s_setprio(1);
  compute256(Al[0], Bl[0], wm, wn, lane, acc);
  __builtin_amdgcn_s_setprio(0);
  VOUT_BAR();
  VOUT_W0(); VOUT_BAR();
  __builtin_amdgcn_s_setprio(1);
  compute256(Al[1], Bl[1], wm, wn, lane, acc);
  __builtin_amdgcn_s_setprio(0);

  const int rr = (lane >> 4) * 4;
  const int cc = lane & 15;
  if (cb < 4) {  // v panel -> origv[b][hd][n] f32 (float4 along n)
    const int nbase = (rb & 31) * 256 + wm * 128;
#pragma unroll
    for (int m = 0; m < 8; ++m)
#pragma unroll
      for (int n = 0; n < 4; ++n) {
        const int hd = cb * 256 + wn * 64 + n * 16 + cc;
        const float4 o4 = make_float4(acc[m][n][0], acc[m][n][1], acc[m][n][2], acc[m][n][3]);
        *(float4*)&origv[((size_t)b * 1024 + hd) * 8192 + nbase + m * 16 + rr] = o4;
      }
  } else {       // out panel -> outp row-major f32
    const size_t grow0 = (size_t)rb * 256 + wm * 128;
    const int gc0 = (cb - 4) * 256 + wn * 64;
#pragma unroll
    for (int m = 0; m < 8; ++m)
#pragma unroll
      for (int n = 0; n < 4; ++n)
#pragma unroll
        for (int j = 0; j < 4; ++j)
          outp[(grow0 + m * 16 + rr + j) * 1024 + gc0 + n * 16 + cc] = acc[m][n][j];
  }
}

// ---------------- norms: qkn2[b*2048+row] = dot(UTt_b[row], wqkvT[row]) --------------
__global__ __launch_bounds__(256) void norms_kernel(const unsigned short* __restrict__ UTt,
                                                    const unsigned short* __restrict__ wqkvT,
                                                    float* __restrict__ qkn2) {
  const int t = threadIdx.x;
  const int rloc = t >> 4, lane16 = t & 15;
  const int row = blockIdx.x * 16 + rloc;
  const int b = row >> 11, r2 = row & 2047;
  const unsigned short* pa = UTt + ((size_t)b << 21) + (size_t)r2 * 1024 + lane16 * 64;
  const unsigned short* pb = wqkvT + (size_t)r2 * 1024 + lane16 * 64;
  float s = 0.f;
  for (int i = 0; i < 64; i += 8) {
    const u16x8 va = *(const u16x8*)&pa[i];
    const u16x8 vb = *(const u16x8*)&pb[i];
#pragma unroll
    for (int j = 0; j < 8; ++j) s += bf2f(va[j]) * bf2f(vb[j]);
  }
  for (int off = 8; off; off >>= 1) s += __shfl_down(s, off, 16);
  if (lane16 == 0) qkn2[row] = s;
}

// ---------------- sim + softmax per (b,h): MFMA 64x64 over K=1024 --------------------
__global__ __launch_bounds__(256) void sim_softmax_kernel(const unsigned short* __restrict__ wqkvT,
                                                          const unsigned short* __restrict__ UTt,
                                                          const float* __restrict__ qkn2,
                                                          const float* __restrict__ temperature,
                                                          float* __restrict__ attn) {
  __shared__ __align__(16) unsigned short Aql[64 * 128];
  __shared__ __align__(16) unsigned short Bkl[64 * 128];
  __shared__ float qknl[2][64];
  const int bh = blockIdx.x;
  const int b = bh >> 4, h = bh & 15;
  const int t = threadIdx.x;
  const int lane = t & 63, w = t >> 6;
  const unsigned short* UTtb = UTt + ((size_t)b << 21);
  if (t < 128) {
    const int sel = t >> 6, dd = t & 63;
    qknl[sel][dd] = fmaxf(sqrtf(qkn2[b * 2048 + sel * 1024 + h * 64 + dd]), 1e-12f);
  }
  const unsigned short* AqG = UTtb + (size_t)(h * 64) * 1024;
  const unsigned short* BkG = wqkvT + (size_t)(1024 + h * 64) * 1024;
  const int r = lane & 15, kg = lane >> 4;
  const int srow = t >> 4, scol = (t & 15) * 8;
  f32x4 acc[4] = {};
  for (int k0 = 0; k0 < 1024; k0 += 128) {
    __syncthreads();
#pragma unroll
    for (int c = 0; c < 4; ++c) {
      gld_lds16(&AqG[(size_t)(c * 16 + srow) * 1024 + k0 + scol], &Aql[c * 2048 + t * 8]);
      gld_lds16(&BkG[(size_t)(c * 16 + srow) * 1024 + k0 + scol], &Bkl[c * 2048 + t * 8]);
    }
    __syncthreads();
#pragma unroll
    for (int kk = 0; kk < 128; kk += 32) {
      const bf16x8 af = *(const bf16x8*)&Aql[(w * 16 + r) * 128 + kk + kg * 8];
#pragma unroll
      for (int n = 0; n < 4; ++n) {
        const bf16x8 bfr = *(const bf16x8*)&Bkl[(n * 16 + r) * 128 + kk + kg * 8];
        acc[n] = __builtin_amdgcn_mfma_f32_16x16x32_bf16(af, bfr, acc[n], 0, 0, 0);
      }
    }
  }
  const float sc = 8.f * __expf(temperature[h]);
  const int colq = lane & 15, rq = lane >> 4;
#pragma unroll
  for (int j = 0; j < 4; ++j) {
    const int d = w * 16 + rq * 4 + j;
    const float qd = qknl[0][d];
    float sv[4];
#pragma unroll
    for (int n = 0; n < 4; ++n) sv[n] = acc[n][j] * sc / (qd * qknl[1][n * 16 + colq]);
    float mj = fmaxf(fmaxf(sv[0], sv[1]), fmaxf(sv[2], sv[3]));
    for (int msk = 1; msk < 16; msk <<= 1) mj = fmaxf(mj, __shfl_xor(mj, msk));
    float p[4], sum = 0.f;
#pragma unroll
    for (int n = 0; n < 4; ++n) { p[n] = __expf(sv[n] - mj); sum += p[n]; }
    for (int msk = 1; msk < 16; msk <<= 1) sum += __shfl_xor(sum, msk);
    const float inv = 1.f / sum;
#pragma unroll
    for (int n = 0; n < 4; ++n)
      attn[(size_t)bh * 4096 + d * 64 + n * 16 + colq] = p[n] * inv;
  }
}

// ---------------- W2T[b][c][h64+e] = sum_d attn[bh][d][e] * w_out[h64+d][c] ----------
__global__ __launch_bounds__(256) void w2t_kernel(const float* __restrict__ attn,
                                                  const float* __restrict__ w_out,
                                                  unsigned short* __restrict__ W2T) {
  __shared__ float al[64][64];
  __shared__ float wl[64][64];
  const int bh = blockIdx.y;
  const int b = bh >> 4, h = bh & 15;
  const int c0 = blockIdx.x * 256;
  const int t = threadIdx.x, e = t & 63, g = t >> 6;
  const int dr = t >> 2, q4 = (t & 3) * 16;
#pragma unroll
  for (int j = 0; j < 16; j += 4)
    *(float4*)&al[dr][q4 + j] = *(const float4*)&attn[(size_t)bh * 4096 + dr * 64 + q4 + j];
  for (int cbk = 0; cbk < 4; ++cbk) {
    __syncthreads();
#pragma unroll
    for (int j = 0; j < 16; j += 4)
      *(float4*)&wl[dr][q4 + j] = *(const float4*)&w_out[(size_t)(h * 64 + dr) * 1024 + c0 + cbk * 64 + q4 + j];
    __syncthreads();
#pragma unroll
    for (int i = 0; i < 16; ++i) {
      const int cc = g * 16 + i;
      float s = 0.f;
#pragma unroll 8
      for (int d = 0; d < 64; ++d) s += al[d][e] * wl[d][cc];
      W2T[((size_t)b << 20) + (size_t)(c0 + cbk * 64 + cc) * 1024 + h * 64 + e] = f2bf(s);
    }
  }
}

extern "C" void kernel_launch(void* const* d_in, const int* in_sizes, int n_in,
                              void* d_out, int out_size, void* d_ws, size_t ws_size,
                              hipStream_t stream) {
  const float* x     = (const float*)d_in[0];
  const float* gamma = (const float*)d_in[1];
  const float* w_qkv = (const float*)d_in[2];
  const float* temp  = (const float*)d_in[3];
  const float* w_out = (const float*)d_in[4];
  char* ws = (char*)d_ws;
  unsigned short* wqkvT  = (unsigned short*)(ws);                 // [3072][1024] bf16
  unsigned short* Wv_nt  = (unsigned short*)(ws + 6291456);       // [1024][1024] bf16
  unsigned short* xn     = (unsigned short*)(ws + 8388608);       // [32768][1024] bf16
  unsigned short* xnT    = (unsigned short*)(ws + 75497472);      // [1024][32768] bf16
  unsigned short* Gp     = (unsigned short*)(ws + 142606336);     // [16][1024][1024] bf16
  unsigned short* G      = (unsigned short*)(ws + 176160768);     // [4][1024][1024] bf16
  unsigned short* UTt    = (unsigned short*)(ws + 184549376);     // [4][2048][1024] bf16
  float* qkn2            = (float*)(ws + 201326592);              // [4][2048] f32
  float* attn            = (float*)(ws + 201359360);              // [64][64][64] f32
  unsigned short* W2T    = (unsigned short*)(ws + 202407936);     // [4][1024][1024] bf16
  unsigned short* WfoldT = (unsigned short*)(ws + 210796544);     // [4][1024][1024] bf16
  float* outp  = (float*)d_out;                                   // out: [4,8192,1024] f32
  float* origv = outp + (size_t)33554432;                         // orig_v: [4,16,64,8192] f32

  transpose_cast_kernel<<<dim3(96, 32), 256, 0, stream>>>(w_qkv, wqkvT, 1024, 3072);
  castv_kernel<<<1024, 256, 0, stream>>>(w_qkv, Wv_nt);
  rmsnorm_kernel<<<32768, 256, 0, stream>>>(x, gamma, xn);
  transpose_bf16x4_kernel<<<dim3(512, 16), 256, 0, stream>>>(xn, xnT);
  gemm_gram_kernel<<<dim3(8, 8, 16), 256, 0, stream>>>(xnT, Gp);
  greduce_kernel<<<dim3(16, 16, 4), 256, 0, stream>>>(Gp, G);
  gemm_bt_batch_bf16<<<dim3(8, 16, 4), 256, 0, stream>>>(wqkvT, G, UTt, 1024, 1024,
                                                         0LL, 1LL << 20, 1LL << 21);
  norms_kernel<<<512, 256, 0, stream>>>(UTt, wqkvT, qkn2);
  sim_softmax_kernel<<<64, 256, 0, stream>>>(wqkvT, UTt, qkn2, temp, attn);
  w2t_kernel<<<dim3(4, 64), 256, 0, stream>>>(attn, w_out, W2T);
  gemm_bt_batch_bf16<<<dim3(8, 8, 4), 256, 0, stream>>>(W2T, Wv_nt, WfoldT, 1024, 1024,
                                                        1LL << 20, 0LL, 1LL << 20);
  gemm_vout256_kernel<<<1024, 512, 0, stream>>>(xn, wqkvT + (size_t)2048 * 1024, WfoldT,
                                                origv, outp);
}